// Round 14
// baseline (119.171 us; speedup 1.0000x reference)
//
#include <hip/hip_runtime.h>

typedef unsigned int u32;
typedef unsigned short u16;
typedef unsigned long long u64;

#define NB 16
#define NA 242991
#define NSEL 4741

__device__ __constant__ int c_LN[5]   = {182400, 45600, 11400, 2850, 741};
__device__ __constant__ int c_LOFF[5] = {0, 182400, 228000, 239400, 242250};
__device__ __constant__ int c_LK[5]   = {1000, 1000, 1000, 1000, 741};
__device__ __constant__ int c_SOFF[5] = {0, 1000, 2000, 3000, 4000};
__device__ __constant__ int c_CST[5]  = {0, 64, 80, 84, 85};   // chunk start per level
__device__ __constant__ int c_CCN[5]  = {64, 16, 4, 1, 1};     // chunk count per level

// ---- XLA-CPU-replicating transcendentals (bitwise-intent, no FMA contraction) ----

__device__ __forceinline__ float xla_tanhf(float x) {
#pragma clang fp contract(off)
  float t = fminf(fmaxf(x, -9.0f), 9.0f);
  float x2 = t * t;
  float p = -2.76076847742355e-16f;
  p = p * x2 + 2.00018790482477e-13f;
  p = p * x2 + -8.60467152213735e-11f;
  p = p * x2 + 5.12229709037114e-08f;
  p = p * x2 + 1.48572235717979e-05f;
  p = p * x2 + 6.37261928875436e-04f;
  p = p * x2 + 4.89352455891786e-03f;
  p = t * p;
  float q = 1.19825839466702e-06f;
  q = q * x2 + 1.18534705686654e-04f;
  q = q * x2 + 2.26843463243900e-03f;
  q = q * x2 + 4.89352518554385e-03f;
  float r = p / q;
  return (fabsf(x) < 0.0004f) ? x : r;
}

__device__ __forceinline__ float ref_sigmoid(float x) {
#pragma clang fp contract(off)
  float t = 0.5f * x;
  float th = xla_tanhf(t);
  return 0.5f + 0.5f * th;
}

__device__ __forceinline__ float xla_expf(float x) {
#pragma clang fp contract(off)
  float fx = x * 1.44269504088896341f + 0.5f;
  fx = floorf(fx);
  float tmp = fx * 0.693359375f;
  float z = fx * -2.12194440e-4f;
  float r = x - tmp;
  r = r - z;
  float r2 = r * r;
  float y = 1.9875691500e-4f;
  y = y * r + 1.3981999507e-3f;
  y = y * r + 8.3334519073e-3f;
  y = y * r + 4.1665795894e-2f;
  y = y * r + 1.6666665459e-1f;
  y = y * r + 5.0000001201e-1f;
  y = y * r2 + r;
  y = y + 1.0f;
  int k = (int)fx;
  float two_k = __uint_as_float((u32)((k + 127) << 23));
  return y * two_k;
}

// chunk -> (level, base, n) mapping; 86 chunks of 2850 (level boundaries divide)
__device__ __forceinline__ void chunk_map(int c, int& l, int& base, int& n) {
  if (c < 64)      { l = 0; base = c * 2850;                 n = 2850; }
  else if (c < 80) { l = 1; base = 182400 + (c - 64) * 2850; n = 2850; }
  else if (c < 84) { l = 2; base = 228000 + (c - 80) * 2850; n = 2850; }
  else if (c == 84){ l = 3; base = 239400;                   n = 2850; }
  else             { l = 4; base = 242250;                   n = 741;  }
}

// ---- S1: per-chunk u16 histogram slabs (non-atomic global writes, no pre-zero) ----

__global__ void __launch_bounds__(256) k_hist(const float* __restrict__ obj,
                                              u16* __restrict__ ghist) {
  const int c = blockIdx.x, b = blockIdx.y;
  int l, base, n;
  chunk_map(c, l, base, n);
  __shared__ u32 h[4096];
  for (int i = threadIdx.x; i < 4096; i += 256) h[i] = 0;
  __syncthreads();
  const float* src = obj + (size_t)b * NA + base;
  for (int i = threadIdx.x; i < n; i += 256) {
    float s = ref_sigmoid(src[i]);
    atomicAdd(&h[__float_as_uint(s) >> 18], 1u);
  }
  __syncthreads();
  u32* gh = (u32*)(ghist + ((size_t)b * 86 + c) * 4096);
  for (int i = threadIdx.x; i < 2048; i += 256)
    gh[i] = (h[2 * i] & 0xFFFFu) | (h[2 * i + 1] << 16);
}

// ---- S2: per-(b,l) threshold-bin find (sums u16 chunk slabs); zeroes ctrs ----

__global__ void __launch_bounds__(1024) k_thresh(const u16* __restrict__ ghist,
                                                 int2* __restrict__ binfo,
                                                 u32* __restrict__ ctrs) {
  const int l = blockIdx.x, b = blockIdx.y, t = threadIdx.x;
  const int K = c_LK[l];
  const int bl = b * 5 + l;
  if (t == 0) { ctrs[bl] = 0; ctrs[80 + bl] = 0; }
  __shared__ u32 scan[1024];
  __shared__ int sh_b;
  __shared__ u32 sh_G;
  u32 h0 = 0, h1 = 0, h2 = 0, h3 = 0;
  const int cs = c_CST[l], cn = c_CCN[l];
  const u16* base = ghist + (size_t)b * 86 * 4096 + 4 * t;
  for (int cc = 0; cc < cn; ++cc) {
    uint2 v = *(const uint2*)(base + (size_t)(cs + cc) * 4096);
    h0 += v.x & 0xFFFFu; h1 += v.x >> 16;
    h2 += v.y & 0xFFFFu; h3 += v.y >> 16;
  }
  u32 loc = h0 + h1 + h2 + h3;
  scan[t] = loc;
  __syncthreads();
  for (int d = 1; d < 1024; d <<= 1) {
    u32 v = (t + d < 1024) ? scan[t + d] : 0u;
    __syncthreads();
    scan[t] += v;
    __syncthreads();
  }
  u32 S = scan[t];
  u32 above = S - loc;
  if (S >= (u32)K && above < (u32)K) {
    u32 cacc = above;
    u32 cn2 = cacc + h3;
    if (cn2 >= (u32)K) { sh_b = 4 * t + 3; sh_G = cacc; }
    else {
      cacc = cn2; cn2 = cacc + h2;
      if (cn2 >= (u32)K) { sh_b = 4 * t + 2; sh_G = cacc; }
      else {
        cacc = cn2; cn2 = cacc + h1;
        if (cn2 >= (u32)K) { sh_b = 4 * t + 1; sh_G = cacc; }
        else { cacc = cn2; sh_b = 4 * t; sh_G = cacc; }
      }
    }
  }
  __syncthreads();
  if (t == 0) binfo[bl] = make_int2(sh_b, (int)sh_G);
}

// ---- S3: emit selected keys; compact LDS staging ----

__global__ void __launch_bounds__(256) k_emit(const float* __restrict__ obj,
                                              const int2* __restrict__ binfo,
                                              u64* __restrict__ skey,
                                              u64* __restrict__ candg,
                                              u32* __restrict__ ctrs) {
  const int c = blockIdx.x, b = blockIdx.y;
  int l, base, n;
  chunk_map(c, l, base, n);
  const int bl = b * 5 + l;
  const int bstar = binfo[bl].x;
  const float* src = obj + (size_t)b * NA + base;

  __shared__ u64 bufD[1024];
  __shared__ u64 bufC[2048];
  __shared__ u32 cntDC, gbD, gbC;
  if (threadIdx.x == 0) cntDC = 0;
  __syncthreads();

  const int lane = (int)threadIdx.x & 63;
  const u64 lmask_lt = (lane == 0) ? 0ull : ((~0ull) >> (64 - lane));
  const int iters = (n + 255) >> 8;
  for (int it = 0; it < iters; ++it) {
    int i = it * 256 + (int)threadIdx.x;
    bool valid = i < n;
    float s = ref_sigmoid(valid ? src[i] : 0.0f);
    u32 bits = __float_as_uint(s);
    int bin = (int)(bits >> 18);
    bool isD = valid && (bin > bstar);
    bool isC = valid && (bin == bstar);
    u64 mD = __ballot(isD);
    u64 mC = __ballot(isC);
    u32 bDC = 0;
    if (lane == 0) {
      u32 add = (u32)__popcll(mD) | ((u32)__popcll(mC) << 16);
      if (add) bDC = atomicAdd(&cntDC, add);
    }
    bDC = (u32)__shfl((int)bDC, 0, 64);
    u64 key = ((u64)(bits ^ 0xFFFFFFFFu) << 32) | (u32)(base + i);
    if (isD) {
      u32 p = (bDC & 0xFFFFu) + (u32)__popcll(mD & lmask_lt);
      if (p < 1024) bufD[p] = key;
    }
    if (isC) {
      u32 p = (bDC >> 16) + (u32)__popcll(mC & lmask_lt);
      if (p < 2048) bufC[p] = key;
    }
  }
  __syncthreads();
  const u32 nD = cntDC & 0xFFFFu, nC = cntDC >> 16;
  if (threadIdx.x == 0) {
    gbD = atomicAdd(&ctrs[bl], nD);
    gbC = atomicAdd(&ctrs[80 + bl], nC);
  }
  __syncthreads();
  const u32 gD = gbD, gC = gbC;
  u64* dstD = skey + (size_t)b * NSEL + c_SOFF[l] + gD;
  for (u32 i = threadIdx.x; i < nD; i += 256) dstD[i] = bufD[i];
  u64* dstC = candg + (size_t)bl * 2048;
  for (u32 i = threadIdx.x; i < nC; i += 256) {
    u32 p = gC + i;
    if (p < 2048 && i < 2048) dstC[p] = bufC[i];
  }
}

// ---- S4+K3 fused: adaptive-width (1024/2048/4096) hybrid bitonic sort ->
//      sorted top-K, then decode from the sort registers. ----

__device__ __forceinline__ u64 shflx64(u64 v, int d) {
  u32 lo = (u32)v, hi = (u32)(v >> 32);
  lo = (u32)__shfl_xor((int)lo, d, 64);
  hi = (u32)__shfl_xor((int)hi, d, 64);
  return ((u64)hi << 32) | (u64)lo;
}

template <int CTRL>
__device__ __forceinline__ u64 dpp64(u64 v) {
  u32 lo = (u32)__builtin_amdgcn_mov_dpp((int)(u32)v, CTRL, 0xF, 0xF, true);
  u32 hi = (u32)__builtin_amdgcn_mov_dpp((int)(u32)(v >> 32), CTRL, 0xF, 0xF, true);
  return ((u64)hi << 32) | (u64)lo;
}

__global__ void __launch_bounds__(1024) k_selsort(
    const u64* __restrict__ candg, const int2* __restrict__ binfo,
    const u32* __restrict__ ctrs, u64* __restrict__ skey,
    const float* __restrict__ reg, const float* __restrict__ priors,
    float* __restrict__ boxes, float* __restrict__ scoref,
    float* __restrict__ nmsbox, u64* __restrict__ sow) {
  const int l = blockIdx.x, b = blockIdx.y, t = threadIdx.x;
  const int bl = b * 5 + l;
  const int K = c_LK[l];
  const int G = binfo[bl].y;
  u32 cc = ctrs[80 + bl];
  if (cc > 2048) cc = 2048;
  __shared__ u64 sm[4096];
  __shared__ u64 sh_sow[16];
  if (t < 16) sh_sow[t] = 0ull;
  const u64* seg = skey + (size_t)b * NSEL + c_SOFF[l];
  const u64* cnd = candg + (size_t)bl * 2048;

  const int total = G + (int)cc;
  const int NS = (total <= 1024) ? 1024 : (total <= 2048) ? 2048 : 4096;
  const int Q = NS >> 2;
  const bool act = (t < Q);
  const int i0 = 4 * t;

  u64 v0 = ~0ull, v1 = ~0ull, v2 = ~0ull, v3 = ~0ull;
  if (act) {
    auto ld = [&](int i) -> u64 {
      if (i < G) return seg[i];
      int ci = i - G;
      return (ci < (int)cc) ? cnd[ci] : ~0ull;
    };
    v0 = ld(i0); v1 = ld(i0 + 1); v2 = ld(i0 + 2); v3 = ld(i0 + 3);
  }

  auto cs = [](u64& a, u64& b2, bool up) {
    if ((a > b2) == up) { u64 x = a; a = b2; b2 = x; }
  };

  if (act) {
    cs(v0, v1, true);
    cs(v2, v3, false);
    bool up = ((i0 & 4) == 0);
    cs(v0, v2, up); cs(v1, v3, up);
    cs(v0, v1, up); cs(v2, v3, up);
  }
  for (int k = 8; k <= NS; k <<= 1) {
    const bool up = ((i0 & k) == 0);
    for (int j = k >> 1; j >= 256; j >>= 1) {
      if (act) { sm[t] = v0; sm[Q + t] = v1; sm[2 * Q + t] = v2; sm[3 * Q + t] = v3; }
      __syncthreads();
      if (act) {
        const int u = t ^ (j >> 2);
        u64 o0 = sm[u], o1 = sm[Q + u], o2 = sm[2 * Q + u], o3 = sm[3 * Q + u];
        const bool keepmin = (((i0 & j) == 0) == up);
        v0 = keepmin ? (v0 < o0 ? v0 : o0) : (v0 > o0 ? v0 : o0);
        v1 = keepmin ? (v1 < o1 ? v1 : o1) : (v1 > o1 ? v1 : o1);
        v2 = keepmin ? (v2 < o2 ? v2 : o2) : (v2 > o2 ? v2 : o2);
        v3 = keepmin ? (v3 < o3 ? v3 : o3) : (v3 > o3 ? v3 : o3);
      }
      __syncthreads();
    }
    if (act) {
      int jstart = (k >> 1) < 128 ? (k >> 1) : 128;
      for (int j = jstart; j >= 4; j >>= 1) {
        const int d = j >> 2;
        u64 o0, o1, o2, o3;
        if (d == 1) {
          o0 = dpp64<0xB1>(v0); o1 = dpp64<0xB1>(v1);
          o2 = dpp64<0xB1>(v2); o3 = dpp64<0xB1>(v3);
        } else if (d == 2) {
          o0 = dpp64<0x4E>(v0); o1 = dpp64<0x4E>(v1);
          o2 = dpp64<0x4E>(v2); o3 = dpp64<0x4E>(v3);
        } else {
          o0 = shflx64(v0, d); o1 = shflx64(v1, d);
          o2 = shflx64(v2, d); o3 = shflx64(v3, d);
        }
        const bool keepmin = (((t & d) == 0) == up);
        v0 = keepmin ? (v0 < o0 ? v0 : o0) : (v0 > o0 ? v0 : o0);
        v1 = keepmin ? (v1 < o1 ? v1 : o1) : (v1 > o1 ? v1 : o1);
        v2 = keepmin ? (v2 < o2 ? v2 : o2) : (v2 > o2 ? v2 : o2);
        v3 = keepmin ? (v3 < o3 ? v3 : o3) : (v3 > o3 ? v3 : o3);
      }
      cs(v0, v2, up); cs(v1, v3, up);
      cs(v0, v1, up); cs(v2, v3, up);
    }
  }

  u64* dst = skey + (size_t)b * NSEL + c_SOFF[l];

  // decode (identical arithmetic), straight from registers (ranks 4t..4t+3)
  {
#pragma clang fp contract(off)
    const float lf = (float)l * 10000.0f;
    u64 kv[4] = {v0, v1, v2, v3};
#pragma unroll
    for (int e = 0; e < 4; ++e) {
      int r = i0 + e;
      if (r < K) {
        u64 kk = kv[e];
        dst[r] = kk;
        u32 idx = (u32)kk;
        if (idx >= (u32)NA) idx = NA - 1;
        u32 bits = (u32)(kk >> 32) ^ 0xFFFFFFFFu;
        float s = __uint_as_float(bits);
        float4 r4 = ((const float4*)reg)[(size_t)b * NA + idx];
        float4 q4 = ((const float4*)priors)[idx];
        float pw = q4.z - q4.x;
        float ph = q4.w - q4.y;
        float pcx = q4.x + 0.5f * pw;
        float pcy = q4.y + 0.5f * ph;
        float dw = fminf(r4.z, 4.135166556742356f);
        float dh = fminf(r4.w, 4.135166556742356f);
        float cx = r4.x * pw + pcx;
        float cy = r4.y * ph + pcy;
        float w = pw * xla_expf(dw);
        float h = ph * xla_expf(dh);
        float x1 = cx - 0.5f * w;
        float y1 = cy - 0.5f * h;
        float x2 = cx + 0.5f * w;
        float y2 = cy + 0.5f * h;
        x1 = fminf(fmaxf(x1, 0.0f), 1216.0f);
        y1 = fminf(fmaxf(y1, 0.0f), 800.0f);
        x2 = fminf(fmaxf(x2, 0.0f), 1216.0f);
        y2 = fminf(fmaxf(y2, 0.0f), 800.0f);
        bool ok = ((x2 - x1) > 0.01f) && ((y2 - y1) > 0.01f);
        int sidx = c_SOFF[l] + r;
        ((float4*)boxes)[(size_t)b * NSEL + sidx] = make_float4(x1, y1, x2, y2);
        scoref[(size_t)b * NSEL + sidx] = s;
        ((float4*)nmsbox)[(size_t)(b * 5 + l) * 1000 + r] =
            make_float4(x1 + lf, y1 + lf, x2 + lf, y2 + lf);
        if (ok) atomicOr(&sh_sow[r >> 6], 1ull << (r & 63));
      }
    }
  }
  __syncthreads();
  if (t < 16) sow[(size_t)b * 80 + l * 16 + t] = sh_sow[t];
}

// ---- NMS phase A: upper-triangle 64x64 tiles, one wave per tile ----
// Gate: sup requires inter >= ~0.6999997*ra (since inter<=min(ra,aj) exactly
// by RN-monotonicity, so den>=ra(1-3eps)); inter<=RN(0.69f*ra)<=0.6900002*ra
// implies sup=false -> gate-skipped lanes are exactly the sup=false ones.

__device__ __forceinline__ void tile_map(int k, int& l, int& ti, int& tj) {
  int W;
  if (k < 544) { l = k / 136; k -= l * 136; W = 16; }
  else         { l = 4; k -= 544; W = 12; }
  int a = 0;
  while (k >= W - a) { k -= W - a; a++; }
  ti = a; tj = a + k;
}

__global__ void __launch_bounds__(256) k_nms_build(const float* __restrict__ nmsbox,
                                                   u64* __restrict__ mk) {
#pragma clang fp contract(off)
  const int b = blockIdx.y;
  const int wv = (int)threadIdx.x >> 6;
  const int tid = blockIdx.x * 4 + wv;
  __shared__ float4 cbox[4][64];
  __shared__ float car[4][64];
  if (tid >= 622) return;
  const int lane = (int)threadIdx.x & 63;
  int l, ti, tj;
  tile_map(tid, l, ti, tj);
  const int N = c_LK[l];
  const int bl = b * 5 + l;
  const float4* src = (const float4*)(nmsbox + (size_t)bl * 4000);
  const int i = ti * 64 + lane;
  const int j = tj * 64 + lane;
  const int il = (i < N) ? i : (N - 1);
  const int jl = (j < N) ? j : (N - 1);
  float4 rb = src[il];
  float4 cb0 = src[jl];
  float ra = fmaxf(rb.z - rb.x, 0.0f) * fmaxf(rb.w - rb.y, 0.0f);
  float ca0 = fmaxf(cb0.z - cb0.x, 0.0f) * fmaxf(cb0.w - cb0.y, 0.0f);
  float ra69 = 0.69f * ra;
  cbox[wv][lane] = cb0;
  car[wv][lane] = ca0;
  u32 mlo = 0u, mhi = 0u;
  const double M = 0.7000000178813934326171875;
#pragma unroll
  for (int c = 0; c < 64; ++c) {
    float4 cb = cbox[wv][c];
    float xx1 = fmaxf(rb.x, cb.x);
    float yy1 = fmaxf(rb.y, cb.y);
    float xx2 = fminf(rb.z, cb.z);
    float yy2 = fminf(rb.w, cb.w);
    float inter = fmaxf(xx2 - xx1, 0.0f) * fmaxf(yy2 - yy1, 0.0f);
    if (__any(inter > ra69)) {
      float aj = car[wv][c];
      float den = ((ra + aj) - inter) + 1e-9f;
      bool sup = ((double)inter >= M * (double)den);
      if (c < 32) mlo |= sup ? (1u << c) : 0u;
      else        mhi |= sup ? (1u << (c - 32)) : 0u;
    }
  }
  u64 m = ((u64)mhi << 32) | (u64)mlo;
  if (ti == tj) m &= (lane == 63) ? 0ull : (~0ull << (lane + 1));
  int nc = N - tj * 64;
  if (nc < 64) m &= (1ull << nc) - 1ull;
  if (i < N) mk[(size_t)bl * 16000 + (size_t)tj * 1000 + i] = m;
}

// ---- NMS phase B: 16-wave cooperative greedy scan, one block per (b,l) ----

__global__ void __launch_bounds__(1024) k_nms_scan(const u64* __restrict__ mk,
                                                   const u64* __restrict__ sow,
                                                   u64* __restrict__ keepw) {
  const int bl = blockIdx.x;
  const int b = bl / 5, l = bl % 5;
  const int N = c_LK[l];
  const int W = (N + 63) >> 6;
  const int lane = (int)threadIdx.x & 63;
  const int w = (int)threadIdx.x >> 6;
  const bool act = (w < W);
  __shared__ u64 sh_kept[16];

  const u64* rowp = mk + (size_t)bl * 16000 + (size_t)w * 1000;
  u64 acc = act ? ~sow[(size_t)b * 80 + l * 16 + w] : 0ull;

  u64 diag = 0ull;
  if (act) {
    int rd = w * 64 + lane;
    if (rd < N) diag = rowp[rd];
  }
  u64 nxt = (act && w > 0) ? rowp[lane] : 0ull;

  for (int g = 0; g < 16; ++g) {
    if (g >= W) break;
    u64 cur = nxt;
    if (act && w > g + 1) {
      int r = (g + 1) * 64 + lane;
      nxt = (r < N) ? rowp[r] : 0ull;
    } else {
      nxt = 0ull;
    }
    if (w == g) {
      u64 sup = acc;
      u64 pend = __ballot(diag != 0) & ~sup;
      while (pend) {
        int i = __builtin_ctzll(pend);
        u64 rr = __shfl(diag, i, 64);
        sup |= rr;
        pend &= ~sup;
        pend &= ~(1ull << i);
      }
      acc = sup;
      if (lane == 0) sh_kept[g] = ~sup;
    }
    __syncthreads();
    if (act && w > g) {
      u64 K = sh_kept[g];
      u64 c = ((K >> lane) & 1ull) ? cur : 0ull;
#pragma unroll
      for (int d = 1; d < 64; d <<= 1) c |= __shfl_xor(c, d, 64);
      acc |= c;
    }
    __syncthreads();
  }
  if (act && lane == 0) keepw[(size_t)b * 80 + l * 16 + w] = ~acc;
}

// ---- K5: whole-batch merge-emit (one block per batch; staging done once) ----

__global__ void __launch_bounds__(1024) k_out(const float* __restrict__ boxes,
                                              const float* __restrict__ scoref,
                                              const u64* __restrict__ skey,
                                              const u64* __restrict__ keepw,
                                              float* __restrict__ out) {
  const int b = blockIdx.x, t = threadIdx.x;
  __shared__ u64 sk[NSEL];
  __shared__ u64 kw[80];
  __shared__ u32 pp[5][17];
  __shared__ u32 sh_T;
  for (int i = t; i < NSEL; i += 1024) sk[i] = skey[(size_t)b * NSEL + i];
  if (t < 80) {
    int l2 = t >> 4, w = t & 15;
    int W = (c_LK[l2] + 63) >> 6;
    kw[t] = (w < W) ? keepw[(size_t)b * 80 + t] : 0ull;
  }
  __syncthreads();
  if (t < 5) {
    u32 acc = 0;
    pp[t][0] = 0;
    for (int w = 0; w < 16; ++w) {
      acc += (u32)__popcll(kw[t * 16 + w]);
      pp[t][w + 1] = acc;
    }
  }
  __syncthreads();
  if (t == 0) sh_T = pp[0][16] + pp[1][16] + pp[2][16] + pp[3][16] + pp[4][16];
  __syncthreads();
  const u32 T = sh_T;

  for (int s = t; s < NSEL; s += 1024) {
    int l2 = (s >= 4000) ? 4 : (s / 1000);
    int r = s - c_SOFF[l2];
    u64 word = kw[l2 * 16 + (r >> 6)];
    if ((word >> (r & 63)) & 1ull) {
      u32 rank = pp[l2][r >> 6] +
                 (u32)__popcll(word & ((r & 63) ? ((1ull << (r & 63)) - 1ull) : 0ull));
      u64 key = sk[s];
#pragma unroll
      for (int l3 = 0; l3 < 5; ++l3) {
        if (l3 == l2) continue;
        int lo = 0, hi = c_LK[l3];
        const int base2 = c_SOFF[l3];
        while (lo < hi) {
          int mid = (lo + hi) >> 1;
          if (sk[base2 + mid] < key) lo = mid + 1; else hi = mid;
        }
        u64 w2 = kw[l3 * 16 + (lo >> 6)];
        rank += pp[l3][lo >> 6] +
                (u32)__popcll(w2 & ((lo & 63) ? ((1ull << (lo & 63)) - 1ull) : 0ull));
      }
      if (rank < 1000u) {
        float4 bo = ((const float4*)boxes)[(size_t)b * NSEL + s];
        float* o = out + ((size_t)b * 1000 + rank) * 5;
        o[0] = bo.x; o[1] = bo.y; o[2] = bo.z; o[3] = bo.w;
        o[4] = scoref[(size_t)b * NSEL + s];
      }
    }
  }
  u32 start = (T < 1000u) ? T : 1000u;
  for (u32 i = start + t; i < 1000u; i += 1024u) {
    float* o = out + ((size_t)b * 1000 + i) * 5;
    o[0] = 0.0f; o[1] = 0.0f; o[2] = 0.0f; o[3] = 0.0f; o[4] = 0.0f;
  }
}

// ---- host ----

extern "C" void kernel_launch(void* const* d_in, const int* in_sizes, int n_in,
                              void* d_out, int out_size, void* d_ws, size_t ws_size,
                              hipStream_t stream) {
  const float* reg = (const float*)d_in[0];
  const float* obj = (const float*)d_in[1];
  const float* priors = (const float*)d_in[2];
  float* out = (float*)d_out;

  char* ws = (char*)d_ws;
  size_t off = 0;
  auto alloc = [&](size_t bytes) {
    size_t r = off;
    off += (bytes + 255) & ~(size_t)255;
    return r;
  };
  u16* ghist = (u16*)(ws + alloc((size_t)NB * 86 * 4096 * 2));
  u32* ctrs = (u32*)(ws + alloc(160 * 4));
  int2* binfo = (int2*)(ws + alloc(80 * 8));
  u64* candg = (u64*)(ws + alloc((size_t)80 * 2048 * 8));
  u64* skey = (u64*)(ws + alloc((size_t)NB * NSEL * 8));
  float* boxes = (float*)(ws + alloc((size_t)NB * NSEL * 16));
  float* scoref = (float*)(ws + alloc((size_t)NB * NSEL * 4));
  float* nmsbox = (float*)(ws + alloc((size_t)NB * 5 * 1000 * 16));
  u64* sow = (u64*)(ws + alloc((size_t)NB * 80 * 8));
  u64* keepw = (u64*)(ws + alloc((size_t)NB * 80 * 8));
  u64* mk = (u64*)(ws + alloc((size_t)80 * 1000 * 16 * 8));

  k_hist<<<dim3(86, NB), 256, 0, stream>>>(obj, ghist);
  k_thresh<<<dim3(5, NB), 1024, 0, stream>>>(ghist, binfo, ctrs);
  k_emit<<<dim3(86, NB), 256, 0, stream>>>(obj, binfo, skey, candg, ctrs);
  k_selsort<<<dim3(5, NB), 1024, 0, stream>>>(candg, binfo, ctrs, skey, reg,
                                              priors, boxes, scoref, nmsbox, sow);
  k_nms_build<<<dim3(156, NB), 256, 0, stream>>>(nmsbox, mk);
  k_nms_scan<<<dim3(80), 1024, 0, stream>>>(mk, sow, keepw);
  k_out<<<dim3(NB), 1024, 0, stream>>>(boxes, scoref, skey, keepw, out);
}

// Round 15
// 107.140 us; speedup vs baseline: 1.1123x; 1.1123x over previous
//
#include <hip/hip_runtime.h>

typedef unsigned int u32;
typedef unsigned short u16;
typedef unsigned long long u64;

#define NB 16
#define NA 242991
#define NSEL 4741

__device__ __constant__ int c_LN[5]   = {182400, 45600, 11400, 2850, 741};
__device__ __constant__ int c_LOFF[5] = {0, 182400, 228000, 239400, 242250};
__device__ __constant__ int c_LK[5]   = {1000, 1000, 1000, 1000, 741};
__device__ __constant__ int c_SOFF[5] = {0, 1000, 2000, 3000, 4000};
__device__ __constant__ int c_CST[5]  = {0, 64, 80, 84, 85};   // chunk start per level
__device__ __constant__ int c_CCN[5]  = {64, 16, 4, 1, 1};     // chunk count per level

// ---- XLA-CPU-replicating transcendentals (bitwise-intent, no FMA contraction) ----

__device__ __forceinline__ float xla_tanhf(float x) {
#pragma clang fp contract(off)
  float t = fminf(fmaxf(x, -9.0f), 9.0f);
  float x2 = t * t;
  float p = -2.76076847742355e-16f;
  p = p * x2 + 2.00018790482477e-13f;
  p = p * x2 + -8.60467152213735e-11f;
  p = p * x2 + 5.12229709037114e-08f;
  p = p * x2 + 1.48572235717979e-05f;
  p = p * x2 + 6.37261928875436e-04f;
  p = p * x2 + 4.89352455891786e-03f;
  p = t * p;
  float q = 1.19825839466702e-06f;
  q = q * x2 + 1.18534705686654e-04f;
  q = q * x2 + 2.26843463243900e-03f;
  q = q * x2 + 4.89352518554385e-03f;
  float r = p / q;
  return (fabsf(x) < 0.0004f) ? x : r;
}

__device__ __forceinline__ float ref_sigmoid(float x) {
#pragma clang fp contract(off)
  float t = 0.5f * x;
  float th = xla_tanhf(t);
  return 0.5f + 0.5f * th;
}

__device__ __forceinline__ float xla_expf(float x) {
#pragma clang fp contract(off)
  float fx = x * 1.44269504088896341f + 0.5f;
  fx = floorf(fx);
  float tmp = fx * 0.693359375f;
  float z = fx * -2.12194440e-4f;
  float r = x - tmp;
  r = r - z;
  float r2 = r * r;
  float y = 1.9875691500e-4f;
  y = y * r + 1.3981999507e-3f;
  y = y * r + 8.3334519073e-3f;
  y = y * r + 4.1665795894e-2f;
  y = y * r + 1.6666665459e-1f;
  y = y * r + 5.0000001201e-1f;
  y = y * r2 + r;
  y = y + 1.0f;
  int k = (int)fx;
  float two_k = __uint_as_float((u32)((k + 127) << 23));
  return y * two_k;
}

// chunk -> (level, base, n) mapping; 86 chunks of 2850 (level boundaries divide)
__device__ __forceinline__ void chunk_map(int c, int& l, int& base, int& n) {
  if (c < 64)      { l = 0; base = c * 2850;                 n = 2850; }
  else if (c < 80) { l = 1; base = 182400 + (c - 64) * 2850; n = 2850; }
  else if (c < 84) { l = 2; base = 228000 + (c - 80) * 2850; n = 2850; }
  else if (c == 84){ l = 3; base = 239400;                   n = 2850; }
  else             { l = 4; base = 242250;                   n = 741;  }
}

// ---- S1: per-chunk u16 histogram slabs (non-atomic global writes, no pre-zero) ----

__global__ void __launch_bounds__(256) k_hist(const float* __restrict__ obj,
                                              u16* __restrict__ ghist) {
  const int c = blockIdx.x, b = blockIdx.y;
  int l, base, n;
  chunk_map(c, l, base, n);
  __shared__ u32 h[4096];
  for (int i = threadIdx.x; i < 4096; i += 256) h[i] = 0;
  __syncthreads();
  const float* src = obj + (size_t)b * NA + base;
  for (int i = threadIdx.x; i < n; i += 256) {
    float s = ref_sigmoid(src[i]);
    atomicAdd(&h[__float_as_uint(s) >> 18], 1u);
  }
  __syncthreads();
  u32* gh = (u32*)(ghist + ((size_t)b * 86 + c) * 4096);
  for (int i = threadIdx.x; i < 2048; i += 256)
    gh[i] = (h[2 * i] & 0xFFFFu) | (h[2 * i + 1] << 16);
}

// ---- S2: per-(b,l) threshold-bin find (sums u16 chunk slabs); zeroes ctrs ----

__global__ void __launch_bounds__(1024) k_thresh(const u16* __restrict__ ghist,
                                                 int2* __restrict__ binfo,
                                                 u32* __restrict__ ctrs) {
  const int l = blockIdx.x, b = blockIdx.y, t = threadIdx.x;
  const int K = c_LK[l];
  const int bl = b * 5 + l;
  if (t == 0) { ctrs[bl] = 0; ctrs[80 + bl] = 0; }
  __shared__ u32 scan[1024];
  __shared__ int sh_b;
  __shared__ u32 sh_G;
  u32 h0 = 0, h1 = 0, h2 = 0, h3 = 0;
  const int cs = c_CST[l], cn = c_CCN[l];
  const u16* base = ghist + (size_t)b * 86 * 4096 + 4 * t;
  for (int cc = 0; cc < cn; ++cc) {
    uint2 v = *(const uint2*)(base + (size_t)(cs + cc) * 4096);
    h0 += v.x & 0xFFFFu; h1 += v.x >> 16;
    h2 += v.y & 0xFFFFu; h3 += v.y >> 16;
  }
  u32 loc = h0 + h1 + h2 + h3;
  scan[t] = loc;
  __syncthreads();
  for (int d = 1; d < 1024; d <<= 1) {
    u32 v = (t + d < 1024) ? scan[t + d] : 0u;
    __syncthreads();
    scan[t] += v;
    __syncthreads();
  }
  u32 S = scan[t];
  u32 above = S - loc;
  if (S >= (u32)K && above < (u32)K) {
    u32 cacc = above;
    u32 cn2 = cacc + h3;
    if (cn2 >= (u32)K) { sh_b = 4 * t + 3; sh_G = cacc; }
    else {
      cacc = cn2; cn2 = cacc + h2;
      if (cn2 >= (u32)K) { sh_b = 4 * t + 2; sh_G = cacc; }
      else {
        cacc = cn2; cn2 = cacc + h1;
        if (cn2 >= (u32)K) { sh_b = 4 * t + 1; sh_G = cacc; }
        else { cacc = cn2; sh_b = 4 * t; sh_G = cacc; }
      }
    }
  }
  __syncthreads();
  if (t == 0) binfo[bl] = make_int2(sh_b, (int)sh_G);
}

// ---- S3: emit selected keys; compact LDS staging ----

__global__ void __launch_bounds__(256) k_emit(const float* __restrict__ obj,
                                              const int2* __restrict__ binfo,
                                              u64* __restrict__ skey,
                                              u64* __restrict__ candg,
                                              u32* __restrict__ ctrs) {
  const int c = blockIdx.x, b = blockIdx.y;
  int l, base, n;
  chunk_map(c, l, base, n);
  const int bl = b * 5 + l;
  const int bstar = binfo[bl].x;
  const float* src = obj + (size_t)b * NA + base;

  __shared__ u64 bufD[1024];
  __shared__ u64 bufC[2048];
  __shared__ u32 cntDC, gbD, gbC;
  if (threadIdx.x == 0) cntDC = 0;
  __syncthreads();

  const int lane = (int)threadIdx.x & 63;
  const u64 lmask_lt = (lane == 0) ? 0ull : ((~0ull) >> (64 - lane));
  const int iters = (n + 255) >> 8;
  for (int it = 0; it < iters; ++it) {
    int i = it * 256 + (int)threadIdx.x;
    bool valid = i < n;
    float s = ref_sigmoid(valid ? src[i] : 0.0f);
    u32 bits = __float_as_uint(s);
    int bin = (int)(bits >> 18);
    bool isD = valid && (bin > bstar);
    bool isC = valid && (bin == bstar);
    u64 mD = __ballot(isD);
    u64 mC = __ballot(isC);
    u32 bDC = 0;
    if (lane == 0) {
      u32 add = (u32)__popcll(mD) | ((u32)__popcll(mC) << 16);
      if (add) bDC = atomicAdd(&cntDC, add);
    }
    bDC = (u32)__shfl((int)bDC, 0, 64);
    u64 key = ((u64)(bits ^ 0xFFFFFFFFu) << 32) | (u32)(base + i);
    if (isD) {
      u32 p = (bDC & 0xFFFFu) + (u32)__popcll(mD & lmask_lt);
      if (p < 1024) bufD[p] = key;
    }
    if (isC) {
      u32 p = (bDC >> 16) + (u32)__popcll(mC & lmask_lt);
      if (p < 2048) bufC[p] = key;
    }
  }
  __syncthreads();
  const u32 nD = cntDC & 0xFFFFu, nC = cntDC >> 16;
  if (threadIdx.x == 0) {
    gbD = atomicAdd(&ctrs[bl], nD);
    gbC = atomicAdd(&ctrs[80 + bl], nC);
  }
  __syncthreads();
  const u32 gD = gbD, gC = gbC;
  u64* dstD = skey + (size_t)b * NSEL + c_SOFF[l] + gD;
  for (u32 i = threadIdx.x; i < nD; i += 256) dstD[i] = bufD[i];
  u64* dstC = candg + (size_t)bl * 2048;
  for (u32 i = threadIdx.x; i < nC; i += 256) {
    u32 p = gC + i;
    if (p < 2048 && i < 2048) dstC[p] = bufC[i];
  }
}

// ---- S4+K3 fused: adaptive-width (1024/2048/4096) hybrid bitonic sort ->
//      sorted top-K, then decode from the sort registers. ----

__device__ __forceinline__ u64 shflx64(u64 v, int d) {
  u32 lo = (u32)v, hi = (u32)(v >> 32);
  lo = (u32)__shfl_xor((int)lo, d, 64);
  hi = (u32)__shfl_xor((int)hi, d, 64);
  return ((u64)hi << 32) | (u64)lo;
}

template <int CTRL>
__device__ __forceinline__ u64 dpp64(u64 v) {
  u32 lo = (u32)__builtin_amdgcn_mov_dpp((int)(u32)v, CTRL, 0xF, 0xF, true);
  u32 hi = (u32)__builtin_amdgcn_mov_dpp((int)(u32)(v >> 32), CTRL, 0xF, 0xF, true);
  return ((u64)hi << 32) | (u64)lo;
}

__global__ void __launch_bounds__(1024) k_selsort(
    const u64* __restrict__ candg, const int2* __restrict__ binfo,
    const u32* __restrict__ ctrs, u64* __restrict__ skey,
    const float* __restrict__ reg, const float* __restrict__ priors,
    float* __restrict__ boxes, float* __restrict__ scoref,
    float* __restrict__ nmsbox, u64* __restrict__ sow) {
  const int l = blockIdx.x, b = blockIdx.y, t = threadIdx.x;
  const int bl = b * 5 + l;
  const int K = c_LK[l];
  const int G = binfo[bl].y;
  u32 cc = ctrs[80 + bl];
  if (cc > 2048) cc = 2048;
  __shared__ u64 sm[4096];
  __shared__ u64 sh_sow[16];
  if (t < 16) sh_sow[t] = 0ull;
  const u64* seg = skey + (size_t)b * NSEL + c_SOFF[l];
  const u64* cnd = candg + (size_t)bl * 2048;

  const int total = G + (int)cc;
  const int NS = (total <= 1024) ? 1024 : (total <= 2048) ? 2048 : 4096;
  const int Q = NS >> 2;
  const bool act = (t < Q);
  const int i0 = 4 * t;

  u64 v0 = ~0ull, v1 = ~0ull, v2 = ~0ull, v3 = ~0ull;
  if (act) {
    auto ld = [&](int i) -> u64 {
      if (i < G) return seg[i];
      int ci = i - G;
      return (ci < (int)cc) ? cnd[ci] : ~0ull;
    };
    v0 = ld(i0); v1 = ld(i0 + 1); v2 = ld(i0 + 2); v3 = ld(i0 + 3);
  }

  auto cs = [](u64& a, u64& b2, bool up) {
    if ((a > b2) == up) { u64 x = a; a = b2; b2 = x; }
  };

  if (act) {
    cs(v0, v1, true);
    cs(v2, v3, false);
    bool up = ((i0 & 4) == 0);
    cs(v0, v2, up); cs(v1, v3, up);
    cs(v0, v1, up); cs(v2, v3, up);
  }
  for (int k = 8; k <= NS; k <<= 1) {
    const bool up = ((i0 & k) == 0);
    for (int j = k >> 1; j >= 256; j >>= 1) {
      if (act) { sm[t] = v0; sm[Q + t] = v1; sm[2 * Q + t] = v2; sm[3 * Q + t] = v3; }
      __syncthreads();
      if (act) {
        const int u = t ^ (j >> 2);
        u64 o0 = sm[u], o1 = sm[Q + u], o2 = sm[2 * Q + u], o3 = sm[3 * Q + u];
        const bool keepmin = (((i0 & j) == 0) == up);
        v0 = keepmin ? (v0 < o0 ? v0 : o0) : (v0 > o0 ? v0 : o0);
        v1 = keepmin ? (v1 < o1 ? v1 : o1) : (v1 > o1 ? v1 : o1);
        v2 = keepmin ? (v2 < o2 ? v2 : o2) : (v2 > o2 ? v2 : o2);
        v3 = keepmin ? (v3 < o3 ? v3 : o3) : (v3 > o3 ? v3 : o3);
      }
      __syncthreads();
    }
    if (act) {
      int jstart = (k >> 1) < 128 ? (k >> 1) : 128;
      for (int j = jstart; j >= 4; j >>= 1) {
        const int d = j >> 2;
        u64 o0, o1, o2, o3;
        if (d == 1) {
          o0 = dpp64<0xB1>(v0); o1 = dpp64<0xB1>(v1);
          o2 = dpp64<0xB1>(v2); o3 = dpp64<0xB1>(v3);
        } else if (d == 2) {
          o0 = dpp64<0x4E>(v0); o1 = dpp64<0x4E>(v1);
          o2 = dpp64<0x4E>(v2); o3 = dpp64<0x4E>(v3);
        } else {
          o0 = shflx64(v0, d); o1 = shflx64(v1, d);
          o2 = shflx64(v2, d); o3 = shflx64(v3, d);
        }
        const bool keepmin = (((t & d) == 0) == up);
        v0 = keepmin ? (v0 < o0 ? v0 : o0) : (v0 > o0 ? v0 : o0);
        v1 = keepmin ? (v1 < o1 ? v1 : o1) : (v1 > o1 ? v1 : o1);
        v2 = keepmin ? (v2 < o2 ? v2 : o2) : (v2 > o2 ? v2 : o2);
        v3 = keepmin ? (v3 < o3 ? v3 : o3) : (v3 > o3 ? v3 : o3);
      }
      cs(v0, v2, up); cs(v1, v3, up);
      cs(v0, v1, up); cs(v2, v3, up);
    }
  }

  u64* dst = skey + (size_t)b * NSEL + c_SOFF[l];

  // decode (identical arithmetic), straight from registers (ranks 4t..4t+3)
  {
#pragma clang fp contract(off)
    const float lf = (float)l * 10000.0f;
    u64 kv[4] = {v0, v1, v2, v3};
#pragma unroll
    for (int e = 0; e < 4; ++e) {
      int r = i0 + e;
      if (r < K) {
        u64 kk = kv[e];
        dst[r] = kk;
        u32 idx = (u32)kk;
        if (idx >= (u32)NA) idx = NA - 1;
        u32 bits = (u32)(kk >> 32) ^ 0xFFFFFFFFu;
        float s = __uint_as_float(bits);
        float4 r4 = ((const float4*)reg)[(size_t)b * NA + idx];
        float4 q4 = ((const float4*)priors)[idx];
        float pw = q4.z - q4.x;
        float ph = q4.w - q4.y;
        float pcx = q4.x + 0.5f * pw;
        float pcy = q4.y + 0.5f * ph;
        float dw = fminf(r4.z, 4.135166556742356f);
        float dh = fminf(r4.w, 4.135166556742356f);
        float cx = r4.x * pw + pcx;
        float cy = r4.y * ph + pcy;
        float w = pw * xla_expf(dw);
        float h = ph * xla_expf(dh);
        float x1 = cx - 0.5f * w;
        float y1 = cy - 0.5f * h;
        float x2 = cx + 0.5f * w;
        float y2 = cy + 0.5f * h;
        x1 = fminf(fmaxf(x1, 0.0f), 1216.0f);
        y1 = fminf(fmaxf(y1, 0.0f), 800.0f);
        x2 = fminf(fmaxf(x2, 0.0f), 1216.0f);
        y2 = fminf(fmaxf(y2, 0.0f), 800.0f);
        bool ok = ((x2 - x1) > 0.01f) && ((y2 - y1) > 0.01f);
        int sidx = c_SOFF[l] + r;
        ((float4*)boxes)[(size_t)b * NSEL + sidx] = make_float4(x1, y1, x2, y2);
        scoref[(size_t)b * NSEL + sidx] = s;
        ((float4*)nmsbox)[(size_t)(b * 5 + l) * 1000 + r] =
            make_float4(x1 + lf, y1 + lf, x2 + lf, y2 + lf);
        if (ok) atomicOr(&sh_sow[r >> 6], 1ull << (r & 63));
      }
    }
  }
  __syncthreads();
  if (t < 16) sow[(size_t)b * 80 + l * 16 + t] = sh_sow[t];
}

// ---- NMS phase A: upper-triangle 64x64 tiles, one wave per tile ----
// Gate: sup requires inter >= ~0.6999997*ra (inter<=min(ra,aj) exactly by
// RN-monotonicity => den>=ra(1-3eps)); inter<=RN(0.69f*ra)<=0.6900002*ra
// implies sup=false -> gate-skipped lanes are exactly the sup=false ones.

__device__ __forceinline__ void tile_map(int k, int& l, int& ti, int& tj) {
  int W;
  if (k < 544) { l = k / 136; k -= l * 136; W = 16; }
  else         { l = 4; k -= 544; W = 12; }
  int a = 0;
  while (k >= W - a) { k -= W - a; a++; }
  ti = a; tj = a + k;
}

__global__ void __launch_bounds__(256) k_nms_build(const float* __restrict__ nmsbox,
                                                   u64* __restrict__ mk) {
#pragma clang fp contract(off)
  const int b = blockIdx.y;
  const int wv = (int)threadIdx.x >> 6;
  const int tid = blockIdx.x * 4 + wv;
  __shared__ float4 cbox[4][64];
  __shared__ float car[4][64];
  if (tid >= 622) return;
  const int lane = (int)threadIdx.x & 63;
  int l, ti, tj;
  tile_map(tid, l, ti, tj);
  const int N = c_LK[l];
  const int bl = b * 5 + l;
  const float4* src = (const float4*)(nmsbox + (size_t)bl * 4000);
  const int i = ti * 64 + lane;
  const int j = tj * 64 + lane;
  const int il = (i < N) ? i : (N - 1);
  const int jl = (j < N) ? j : (N - 1);
  float4 rb = src[il];
  float4 cb0 = src[jl];
  float ra = fmaxf(rb.z - rb.x, 0.0f) * fmaxf(rb.w - rb.y, 0.0f);
  float ca0 = fmaxf(cb0.z - cb0.x, 0.0f) * fmaxf(cb0.w - cb0.y, 0.0f);
  float ra69 = 0.69f * ra;
  cbox[wv][lane] = cb0;
  car[wv][lane] = ca0;
  u32 mlo = 0u, mhi = 0u;
  const double M = 0.7000000178813934326171875;
#pragma unroll
  for (int c = 0; c < 64; ++c) {
    float4 cb = cbox[wv][c];
    float xx1 = fmaxf(rb.x, cb.x);
    float yy1 = fmaxf(rb.y, cb.y);
    float xx2 = fminf(rb.z, cb.z);
    float yy2 = fminf(rb.w, cb.w);
    float inter = fmaxf(xx2 - xx1, 0.0f) * fmaxf(yy2 - yy1, 0.0f);
    if (__any(inter > ra69)) {
      float aj = car[wv][c];
      float den = ((ra + aj) - inter) + 1e-9f;
      bool sup = ((double)inter >= M * (double)den);
      if (c < 32) mlo |= sup ? (1u << c) : 0u;
      else        mhi |= sup ? (1u << (c - 32)) : 0u;
    }
  }
  u64 m = ((u64)mhi << 32) | (u64)mlo;
  if (ti == tj) m &= (lane == 63) ? 0ull : (~0ull << (lane + 1));
  int nc = N - tj * 64;
  if (nc < 64) m &= (1ull << nc) - 1ull;
  if (i < N) mk[(size_t)bl * 16000 + (size_t)tj * 1000 + i] = m;
}

// ---- NMS phase B: 16-wave cooperative greedy scan, one block per (b,l) ----

__global__ void __launch_bounds__(1024) k_nms_scan(const u64* __restrict__ mk,
                                                   const u64* __restrict__ sow,
                                                   u64* __restrict__ keepw) {
  const int bl = blockIdx.x;
  const int b = bl / 5, l = bl % 5;
  const int N = c_LK[l];
  const int W = (N + 63) >> 6;
  const int lane = (int)threadIdx.x & 63;
  const int w = (int)threadIdx.x >> 6;
  const bool act = (w < W);
  __shared__ u64 sh_kept[16];

  const u64* rowp = mk + (size_t)bl * 16000 + (size_t)w * 1000;
  u64 acc = act ? ~sow[(size_t)b * 80 + l * 16 + w] : 0ull;

  u64 diag = 0ull;
  if (act) {
    int rd = w * 64 + lane;
    if (rd < N) diag = rowp[rd];
  }
  u64 nxt = (act && w > 0) ? rowp[lane] : 0ull;

  for (int g = 0; g < 16; ++g) {
    if (g >= W) break;
    u64 cur = nxt;
    if (act && w > g + 1) {
      int r = (g + 1) * 64 + lane;
      nxt = (r < N) ? rowp[r] : 0ull;
    } else {
      nxt = 0ull;
    }
    if (w == g) {
      u64 sup = acc;
      u64 pend = __ballot(diag != 0) & ~sup;
      while (pend) {
        int i = __builtin_ctzll(pend);
        u64 rr = __shfl(diag, i, 64);
        sup |= rr;
        pend &= ~sup;
        pend &= ~(1ull << i);
      }
      acc = sup;
      if (lane == 0) sh_kept[g] = ~sup;
    }
    __syncthreads();
    if (act && w > g) {
      u64 K = sh_kept[g];
      u64 c = ((K >> lane) & 1ull) ? cur : 0ull;
#pragma unroll
      for (int d = 1; d < 64; d <<= 1) c |= __shfl_xor(c, d, 64);
      acc |= c;
    }
    __syncthreads();
  }
  if (act && lane == 0) keepw[(size_t)b * 80 + l * 16 + w] = ~acc;
}

// ---- K5: merge 5 sorted kept lists by key; per-(level,batch) blocks ----

__global__ void __launch_bounds__(1024) k_out(const float* __restrict__ boxes,
                                              const float* __restrict__ scoref,
                                              const u64* __restrict__ skey,
                                              const u64* __restrict__ keepw,
                                              float* __restrict__ out) {
  const int l = blockIdx.x, b = blockIdx.y, t = threadIdx.x;
  __shared__ u64 sk[NSEL];
  __shared__ u64 kw[80];
  __shared__ u32 pp[5][17];
  __shared__ u32 sh_T;
  for (int i = t; i < NSEL; i += 1024) sk[i] = skey[(size_t)b * NSEL + i];
  if (t < 80) {
    int l2 = t >> 4, w = t & 15;
    int W = (c_LK[l2] + 63) >> 6;
    kw[t] = (w < W) ? keepw[(size_t)b * 80 + t] : 0ull;
  }
  __syncthreads();
  if (t < 5) {
    u32 acc = 0;
    pp[t][0] = 0;
    for (int w = 0; w < 16; ++w) {
      acc += (u32)__popcll(kw[t * 16 + w]);
      pp[t][w + 1] = acc;
    }
  }
  __syncthreads();
  if (t == 0) sh_T = pp[0][16] + pp[1][16] + pp[2][16] + pp[3][16] + pp[4][16];
  __syncthreads();
  const u32 T = sh_T;
  const int K = c_LK[l];

  for (int r = t; r < K; r += 1024) {
    int s = c_SOFF[l] + r;
    u64 word = kw[l * 16 + (r >> 6)];
    if ((word >> (r & 63)) & 1ull) {
      u32 rank = pp[l][r >> 6] +
                 (u32)__popcll(word & ((r & 63) ? ((1ull << (r & 63)) - 1ull) : 0ull));
      u64 key = sk[s];
#pragma unroll
      for (int l2 = 0; l2 < 5; ++l2) {
        if (l2 == l) continue;
        int lo = 0, hi = c_LK[l2];
        const int base2 = c_SOFF[l2];
        while (lo < hi) {
          int mid = (lo + hi) >> 1;
          if (sk[base2 + mid] < key) lo = mid + 1; else hi = mid;
        }
        u64 w2 = kw[l2 * 16 + (lo >> 6)];
        rank += pp[l2][lo >> 6] +
                (u32)__popcll(w2 & ((lo & 63) ? ((1ull << (lo & 63)) - 1ull) : 0ull));
      }
      if (rank < 1000u) {
        float4 bo = ((const float4*)boxes)[(size_t)b * NSEL + s];
        float* o = out + ((size_t)b * 1000 + rank) * 5;
        o[0] = bo.x; o[1] = bo.y; o[2] = bo.z; o[3] = bo.w;
        o[4] = scoref[(size_t)b * NSEL + s];
      }
    }
  }
  if (l == 0) {
    u32 start = (T < 1000u) ? T : 1000u;
    for (u32 i = start + t; i < 1000u; i += 1024u) {
      float* o = out + ((size_t)b * 1000 + i) * 5;
      o[0] = 0.0f; o[1] = 0.0f; o[2] = 0.0f; o[3] = 0.0f; o[4] = 0.0f;
    }
  }
}

// ---- host ----

extern "C" void kernel_launch(void* const* d_in, const int* in_sizes, int n_in,
                              void* d_out, int out_size, void* d_ws, size_t ws_size,
                              hipStream_t stream) {
  const float* reg = (const float*)d_in[0];
  const float* obj = (const float*)d_in[1];
  const float* priors = (const float*)d_in[2];
  float* out = (float*)d_out;

  char* ws = (char*)d_ws;
  size_t off = 0;
  auto alloc = [&](size_t bytes) {
    size_t r = off;
    off += (bytes + 255) & ~(size_t)255;
    return r;
  };
  u16* ghist = (u16*)(ws + alloc((size_t)NB * 86 * 4096 * 2));
  u32* ctrs = (u32*)(ws + alloc(160 * 4));
  int2* binfo = (int2*)(ws + alloc(80 * 8));
  u64* candg = (u64*)(ws + alloc((size_t)80 * 2048 * 8));
  u64* skey = (u64*)(ws + alloc((size_t)NB * NSEL * 8));
  float* boxes = (float*)(ws + alloc((size_t)NB * NSEL * 16));
  float* scoref = (float*)(ws + alloc((size_t)NB * NSEL * 4));
  float* nmsbox = (float*)(ws + alloc((size_t)NB * 5 * 1000 * 16));
  u64* sow = (u64*)(ws + alloc((size_t)NB * 80 * 8));
  u64* keepw = (u64*)(ws + alloc((size_t)NB * 80 * 8));
  u64* mk = (u64*)(ws + alloc((size_t)80 * 1000 * 16 * 8));

  k_hist<<<dim3(86, NB), 256, 0, stream>>>(obj, ghist);
  k_thresh<<<dim3(5, NB), 1024, 0, stream>>>(ghist, binfo, ctrs);
  k_emit<<<dim3(86, NB), 256, 0, stream>>>(obj, binfo, skey, candg, ctrs);
  k_selsort<<<dim3(5, NB), 1024, 0, stream>>>(candg, binfo, ctrs, skey, reg,
                                              priors, boxes, scoref, nmsbox, sow);
  k_nms_build<<<dim3(156, NB), 256, 0, stream>>>(nmsbox, mk);
  k_nms_scan<<<dim3(80), 1024, 0, stream>>>(mk, sow, keepw);
  k_out<<<dim3(5, NB), 1024, 0, stream>>>(boxes, scoref, skey, keepw, out);
}

// Round 16
// 106.873 us; speedup vs baseline: 1.1151x; 1.0025x over previous
//
#include <hip/hip_runtime.h>

typedef unsigned int u32;
typedef unsigned short u16;
typedef unsigned long long u64;

#define NB 16
#define NA 242991
#define NSEL 4741

__device__ __constant__ int c_LN[5]   = {182400, 45600, 11400, 2850, 741};
__device__ __constant__ int c_LOFF[5] = {0, 182400, 228000, 239400, 242250};
__device__ __constant__ int c_LK[5]   = {1000, 1000, 1000, 1000, 741};
__device__ __constant__ int c_SOFF[5] = {0, 1000, 2000, 3000, 4000};
__device__ __constant__ int c_CST[5]  = {0, 64, 80, 84, 85};   // chunk start per level
__device__ __constant__ int c_CCN[5]  = {64, 16, 4, 1, 1};     // chunk count per level

// ---- XLA-CPU-replicating transcendentals (bitwise-intent, no FMA contraction) ----

__device__ __forceinline__ float xla_tanhf(float x) {
#pragma clang fp contract(off)
  float t = fminf(fmaxf(x, -9.0f), 9.0f);
  float x2 = t * t;
  float p = -2.76076847742355e-16f;
  p = p * x2 + 2.00018790482477e-13f;
  p = p * x2 + -8.60467152213735e-11f;
  p = p * x2 + 5.12229709037114e-08f;
  p = p * x2 + 1.48572235717979e-05f;
  p = p * x2 + 6.37261928875436e-04f;
  p = p * x2 + 4.89352455891786e-03f;
  p = t * p;
  float q = 1.19825839466702e-06f;
  q = q * x2 + 1.18534705686654e-04f;
  q = q * x2 + 2.26843463243900e-03f;
  q = q * x2 + 4.89352518554385e-03f;
  float r = p / q;
  return (fabsf(x) < 0.0004f) ? x : r;
}

__device__ __forceinline__ float ref_sigmoid(float x) {
#pragma clang fp contract(off)
  float t = 0.5f * x;
  float th = xla_tanhf(t);
  return 0.5f + 0.5f * th;
}

__device__ __forceinline__ float xla_expf(float x) {
#pragma clang fp contract(off)
  float fx = x * 1.44269504088896341f + 0.5f;
  fx = floorf(fx);
  float tmp = fx * 0.693359375f;
  float z = fx * -2.12194440e-4f;
  float r = x - tmp;
  r = r - z;
  float r2 = r * r;
  float y = 1.9875691500e-4f;
  y = y * r + 1.3981999507e-3f;
  y = y * r + 8.3334519073e-3f;
  y = y * r + 4.1665795894e-2f;
  y = y * r + 1.6666665459e-1f;
  y = y * r + 5.0000001201e-1f;
  y = y * r2 + r;
  y = y + 1.0f;
  int k = (int)fx;
  float two_k = __uint_as_float((u32)((k + 127) << 23));
  return y * two_k;
}

// chunk -> (level, base, n) mapping; 86 chunks of 2850 (level boundaries divide)
__device__ __forceinline__ void chunk_map(int c, int& l, int& base, int& n) {
  if (c < 64)      { l = 0; base = c * 2850;                 n = 2850; }
  else if (c < 80) { l = 1; base = 182400 + (c - 64) * 2850; n = 2850; }
  else if (c < 84) { l = 2; base = 228000 + (c - 80) * 2850; n = 2850; }
  else if (c == 84){ l = 3; base = 239400;                   n = 2850; }
  else             { l = 4; base = 242250;                   n = 741;  }
}

// ---- S1: per-chunk u16 histogram slabs (non-atomic global writes, no pre-zero) ----

__global__ void __launch_bounds__(256) k_hist(const float* __restrict__ obj,
                                              u16* __restrict__ ghist) {
  const int c = blockIdx.x, b = blockIdx.y;
  int l, base, n;
  chunk_map(c, l, base, n);
  __shared__ u32 h[4096];
  for (int i = threadIdx.x; i < 4096; i += 256) h[i] = 0;
  __syncthreads();
  const float* src = obj + (size_t)b * NA + base;
  for (int i = threadIdx.x; i < n; i += 256) {
    float s = ref_sigmoid(src[i]);
    atomicAdd(&h[__float_as_uint(s) >> 18], 1u);
  }
  __syncthreads();
  u32* gh = (u32*)(ghist + ((size_t)b * 86 + c) * 4096);
  for (int i = threadIdx.x; i < 2048; i += 256)
    gh[i] = (h[2 * i] & 0xFFFFu) | (h[2 * i + 1] << 16);
}

// ---- S2: per-(b,l) threshold-bin find (sums u16 chunk slabs); zeroes ctrs ----

__global__ void __launch_bounds__(1024) k_thresh(const u16* __restrict__ ghist,
                                                 int2* __restrict__ binfo,
                                                 u32* __restrict__ ctrs) {
  const int l = blockIdx.x, b = blockIdx.y, t = threadIdx.x;
  const int K = c_LK[l];
  const int bl = b * 5 + l;
  if (t == 0) { ctrs[bl] = 0; ctrs[80 + bl] = 0; }
  __shared__ u32 scan[1024];
  __shared__ int sh_b;
  __shared__ u32 sh_G;
  u32 h0 = 0, h1 = 0, h2 = 0, h3 = 0;
  const int cs = c_CST[l], cn = c_CCN[l];
  const u16* base = ghist + (size_t)b * 86 * 4096 + 4 * t;
  for (int cc = 0; cc < cn; ++cc) {
    uint2 v = *(const uint2*)(base + (size_t)(cs + cc) * 4096);
    h0 += v.x & 0xFFFFu; h1 += v.x >> 16;
    h2 += v.y & 0xFFFFu; h3 += v.y >> 16;
  }
  u32 loc = h0 + h1 + h2 + h3;
  scan[t] = loc;
  __syncthreads();
  for (int d = 1; d < 1024; d <<= 1) {
    u32 v = (t + d < 1024) ? scan[t + d] : 0u;
    __syncthreads();
    scan[t] += v;
    __syncthreads();
  }
  u32 S = scan[t];
  u32 above = S - loc;
  if (S >= (u32)K && above < (u32)K) {
    u32 cacc = above;
    u32 cn2 = cacc + h3;
    if (cn2 >= (u32)K) { sh_b = 4 * t + 3; sh_G = cacc; }
    else {
      cacc = cn2; cn2 = cacc + h2;
      if (cn2 >= (u32)K) { sh_b = 4 * t + 2; sh_G = cacc; }
      else {
        cacc = cn2; cn2 = cacc + h1;
        if (cn2 >= (u32)K) { sh_b = 4 * t + 1; sh_G = cacc; }
        else { cacc = cn2; sh_b = 4 * t; sh_G = cacc; }
      }
    }
  }
  __syncthreads();
  if (t == 0) binfo[bl] = make_int2(sh_b, (int)sh_G);
}

// ---- S3: emit selected keys; compact LDS staging ----

__global__ void __launch_bounds__(256) k_emit(const float* __restrict__ obj,
                                              const int2* __restrict__ binfo,
                                              u64* __restrict__ skey,
                                              u64* __restrict__ candg,
                                              u32* __restrict__ ctrs) {
  const int c = blockIdx.x, b = blockIdx.y;
  int l, base, n;
  chunk_map(c, l, base, n);
  const int bl = b * 5 + l;
  const int bstar = binfo[bl].x;
  const float* src = obj + (size_t)b * NA + base;

  __shared__ u64 bufD[1024];
  __shared__ u64 bufC[2048];
  __shared__ u32 cntDC, gbD, gbC;
  if (threadIdx.x == 0) cntDC = 0;
  __syncthreads();

  const int lane = (int)threadIdx.x & 63;
  const u64 lmask_lt = (lane == 0) ? 0ull : ((~0ull) >> (64 - lane));
  const int iters = (n + 255) >> 8;
  for (int it = 0; it < iters; ++it) {
    int i = it * 256 + (int)threadIdx.x;
    bool valid = i < n;
    float s = ref_sigmoid(valid ? src[i] : 0.0f);
    u32 bits = __float_as_uint(s);
    int bin = (int)(bits >> 18);
    bool isD = valid && (bin > bstar);
    bool isC = valid && (bin == bstar);
    u64 mD = __ballot(isD);
    u64 mC = __ballot(isC);
    u32 bDC = 0;
    if (lane == 0) {
      u32 add = (u32)__popcll(mD) | ((u32)__popcll(mC) << 16);
      if (add) bDC = atomicAdd(&cntDC, add);
    }
    bDC = (u32)__shfl((int)bDC, 0, 64);
    u64 key = ((u64)(bits ^ 0xFFFFFFFFu) << 32) | (u32)(base + i);
    if (isD) {
      u32 p = (bDC & 0xFFFFu) + (u32)__popcll(mD & lmask_lt);
      if (p < 1024) bufD[p] = key;
    }
    if (isC) {
      u32 p = (bDC >> 16) + (u32)__popcll(mC & lmask_lt);
      if (p < 2048) bufC[p] = key;
    }
  }
  __syncthreads();
  const u32 nD = cntDC & 0xFFFFu, nC = cntDC >> 16;
  if (threadIdx.x == 0) {
    gbD = atomicAdd(&ctrs[bl], nD);
    gbC = atomicAdd(&ctrs[80 + bl], nC);
  }
  __syncthreads();
  const u32 gD = gbD, gC = gbC;
  u64* dstD = skey + (size_t)b * NSEL + c_SOFF[l] + gD;
  for (u32 i = threadIdx.x; i < nD; i += 256) dstD[i] = bufD[i];
  u64* dstC = candg + (size_t)bl * 2048;
  for (u32 i = threadIdx.x; i < nC; i += 256) {
    u32 p = gC + i;
    if (p < 2048 && i < 2048) dstC[p] = bufC[i];
  }
}

// ---- S4+K3 fused: adaptive-width (1024/2048/4096) hybrid bitonic sort ->
//      keys redistributed via LDS -> ALL 1024 threads decode (rank r = t). ----

__device__ __forceinline__ u64 shflx64(u64 v, int d) {
  u32 lo = (u32)v, hi = (u32)(v >> 32);
  lo = (u32)__shfl_xor((int)lo, d, 64);
  hi = (u32)__shfl_xor((int)hi, d, 64);
  return ((u64)hi << 32) | (u64)lo;
}

template <int CTRL>
__device__ __forceinline__ u64 dpp64(u64 v) {
  u32 lo = (u32)__builtin_amdgcn_mov_dpp((int)(u32)v, CTRL, 0xF, 0xF, true);
  u32 hi = (u32)__builtin_amdgcn_mov_dpp((int)(u32)(v >> 32), CTRL, 0xF, 0xF, true);
  return ((u64)hi << 32) | (u64)lo;
}

__global__ void __launch_bounds__(1024) k_selsort(
    const u64* __restrict__ candg, const int2* __restrict__ binfo,
    const u32* __restrict__ ctrs, u64* __restrict__ skey,
    const float* __restrict__ reg, const float* __restrict__ priors,
    float* __restrict__ boxes, float* __restrict__ scoref,
    float* __restrict__ nmsbox, u64* __restrict__ sow) {
  const int l = blockIdx.x, b = blockIdx.y, t = threadIdx.x;
  const int bl = b * 5 + l;
  const int K = c_LK[l];
  const int G = binfo[bl].y;
  u32 cc = ctrs[80 + bl];
  if (cc > 2048) cc = 2048;
  __shared__ u64 sm[4096];
  __shared__ u64 sh_sow[16];
  if (t < 16) sh_sow[t] = 0ull;
  const u64* seg = skey + (size_t)b * NSEL + c_SOFF[l];
  const u64* cnd = candg + (size_t)bl * 2048;

  const int total = G + (int)cc;
  const int NS = (total <= 1024) ? 1024 : (total <= 2048) ? 2048 : 4096;
  const int Q = NS >> 2;
  const bool act = (t < Q);
  const int i0 = 4 * t;

  u64 v0 = ~0ull, v1 = ~0ull, v2 = ~0ull, v3 = ~0ull;
  if (act) {
    auto ld = [&](int i) -> u64 {
      if (i < G) return seg[i];
      int ci = i - G;
      return (ci < (int)cc) ? cnd[ci] : ~0ull;
    };
    v0 = ld(i0); v1 = ld(i0 + 1); v2 = ld(i0 + 2); v3 = ld(i0 + 3);
  }

  auto cs = [](u64& a, u64& b2, bool up) {
    if ((a > b2) == up) { u64 x = a; a = b2; b2 = x; }
  };

  if (act) {
    cs(v0, v1, true);
    cs(v2, v3, false);
    bool up = ((i0 & 4) == 0);
    cs(v0, v2, up); cs(v1, v3, up);
    cs(v0, v1, up); cs(v2, v3, up);
  }
  for (int k = 8; k <= NS; k <<= 1) {
    const bool up = ((i0 & k) == 0);
    for (int j = k >> 1; j >= 256; j >>= 1) {
      if (act) { sm[t] = v0; sm[Q + t] = v1; sm[2 * Q + t] = v2; sm[3 * Q + t] = v3; }
      __syncthreads();
      if (act) {
        const int u = t ^ (j >> 2);
        u64 o0 = sm[u], o1 = sm[Q + u], o2 = sm[2 * Q + u], o3 = sm[3 * Q + u];
        const bool keepmin = (((i0 & j) == 0) == up);
        v0 = keepmin ? (v0 < o0 ? v0 : o0) : (v0 > o0 ? v0 : o0);
        v1 = keepmin ? (v1 < o1 ? v1 : o1) : (v1 > o1 ? v1 : o1);
        v2 = keepmin ? (v2 < o2 ? v2 : o2) : (v2 > o2 ? v2 : o2);
        v3 = keepmin ? (v3 < o3 ? v3 : o3) : (v3 > o3 ? v3 : o3);
      }
      __syncthreads();
    }
    if (act) {
      int jstart = (k >> 1) < 128 ? (k >> 1) : 128;
      for (int j = jstart; j >= 4; j >>= 1) {
        const int d = j >> 2;
        u64 o0, o1, o2, o3;
        if (d == 1) {
          o0 = dpp64<0xB1>(v0); o1 = dpp64<0xB1>(v1);
          o2 = dpp64<0xB1>(v2); o3 = dpp64<0xB1>(v3);
        } else if (d == 2) {
          o0 = dpp64<0x4E>(v0); o1 = dpp64<0x4E>(v1);
          o2 = dpp64<0x4E>(v2); o3 = dpp64<0x4E>(v3);
        } else {
          o0 = shflx64(v0, d); o1 = shflx64(v1, d);
          o2 = shflx64(v2, d); o3 = shflx64(v3, d);
        }
        const bool keepmin = (((t & d) == 0) == up);
        v0 = keepmin ? (v0 < o0 ? v0 : o0) : (v0 > o0 ? v0 : o0);
        v1 = keepmin ? (v1 < o1 ? v1 : o1) : (v1 > o1 ? v1 : o1);
        v2 = keepmin ? (v2 < o2 ? v2 : o2) : (v2 > o2 ? v2 : o2);
        v3 = keepmin ? (v3 < o3 ? v3 : o3) : (v3 > o3 ? v3 : o3);
      }
      cs(v0, v2, up); cs(v1, v3, up);
      cs(v0, v1, up); cs(v2, v3, up);
    }
  }

  // redistribute sorted keys through LDS so ALL 16 waves share the
  // gather-heavy decode (was: only threads with 4t<K, i.e. 4 waves)
  __syncthreads();
  if (act) { sm[i0] = v0; sm[i0 + 1] = v1; sm[i0 + 2] = v2; sm[i0 + 3] = v3; }
  __syncthreads();

  u64* dst = skey + (size_t)b * NSEL + c_SOFF[l];

  // decode (identical arithmetic), rank r = t, one entry per thread
  if (t < K) {
#pragma clang fp contract(off)
    const float lf = (float)l * 10000.0f;
    const int r = t;
    u64 kk = sm[r];
    dst[r] = kk;
    u32 idx = (u32)kk;
    if (idx >= (u32)NA) idx = NA - 1;
    u32 bits = (u32)(kk >> 32) ^ 0xFFFFFFFFu;
    float s = __uint_as_float(bits);
    float4 r4 = ((const float4*)reg)[(size_t)b * NA + idx];
    float4 q4 = ((const float4*)priors)[idx];
    float pw = q4.z - q4.x;
    float ph = q4.w - q4.y;
    float pcx = q4.x + 0.5f * pw;
    float pcy = q4.y + 0.5f * ph;
    float dw = fminf(r4.z, 4.135166556742356f);
    float dh = fminf(r4.w, 4.135166556742356f);
    float cx = r4.x * pw + pcx;
    float cy = r4.y * ph + pcy;
    float w = pw * xla_expf(dw);
    float h = ph * xla_expf(dh);
    float x1 = cx - 0.5f * w;
    float y1 = cy - 0.5f * h;
    float x2 = cx + 0.5f * w;
    float y2 = cy + 0.5f * h;
    x1 = fminf(fmaxf(x1, 0.0f), 1216.0f);
    y1 = fminf(fmaxf(y1, 0.0f), 800.0f);
    x2 = fminf(fmaxf(x2, 0.0f), 1216.0f);
    y2 = fminf(fmaxf(y2, 0.0f), 800.0f);
    bool ok = ((x2 - x1) > 0.01f) && ((y2 - y1) > 0.01f);
    int sidx = c_SOFF[l] + r;
    ((float4*)boxes)[(size_t)b * NSEL + sidx] = make_float4(x1, y1, x2, y2);
    scoref[(size_t)b * NSEL + sidx] = s;
    ((float4*)nmsbox)[(size_t)(b * 5 + l) * 1000 + r] =
        make_float4(x1 + lf, y1 + lf, x2 + lf, y2 + lf);
    if (ok) atomicOr(&sh_sow[r >> 6], 1ull << (r & 63));
  }
  __syncthreads();
  if (t < 16) sow[(size_t)b * 80 + l * 16 + t] = sh_sow[t];
}

// ---- NMS phase A: upper-triangle 64x64 tiles, one wave per tile ----
// Gate: sup requires inter >= ~0.6999997*ra (inter<=min(ra,aj) exactly by
// RN-monotonicity => den>=ra(1-3eps)); inter<=RN(0.69f*ra)<=0.6900002*ra
// implies sup=false -> gate-skipped lanes are exactly the sup=false ones.

__device__ __forceinline__ void tile_map(int k, int& l, int& ti, int& tj) {
  int W;
  if (k < 544) { l = k / 136; k -= l * 136; W = 16; }
  else         { l = 4; k -= 544; W = 12; }
  int a = 0;
  while (k >= W - a) { k -= W - a; a++; }
  ti = a; tj = a + k;
}

__global__ void __launch_bounds__(256) k_nms_build(const float* __restrict__ nmsbox,
                                                   u64* __restrict__ mk) {
#pragma clang fp contract(off)
  const int b = blockIdx.y;
  const int wv = (int)threadIdx.x >> 6;
  const int tid = blockIdx.x * 4 + wv;
  __shared__ float4 cbox[4][64];
  __shared__ float car[4][64];
  if (tid >= 622) return;
  const int lane = (int)threadIdx.x & 63;
  int l, ti, tj;
  tile_map(tid, l, ti, tj);
  const int N = c_LK[l];
  const int bl = b * 5 + l;
  const float4* src = (const float4*)(nmsbox + (size_t)bl * 4000);
  const int i = ti * 64 + lane;
  const int j = tj * 64 + lane;
  const int il = (i < N) ? i : (N - 1);
  const int jl = (j < N) ? j : (N - 1);
  float4 rb = src[il];
  float4 cb0 = src[jl];
  float ra = fmaxf(rb.z - rb.x, 0.0f) * fmaxf(rb.w - rb.y, 0.0f);
  float ca0 = fmaxf(cb0.z - cb0.x, 0.0f) * fmaxf(cb0.w - cb0.y, 0.0f);
  float ra69 = 0.69f * ra;
  cbox[wv][lane] = cb0;
  car[wv][lane] = ca0;
  u32 mlo = 0u, mhi = 0u;
  const double M = 0.7000000178813934326171875;
#pragma unroll
  for (int c = 0; c < 64; ++c) {
    float4 cb = cbox[wv][c];
    float xx1 = fmaxf(rb.x, cb.x);
    float yy1 = fmaxf(rb.y, cb.y);
    float xx2 = fminf(rb.z, cb.z);
    float yy2 = fminf(rb.w, cb.w);
    float inter = fmaxf(xx2 - xx1, 0.0f) * fmaxf(yy2 - yy1, 0.0f);
    if (__any(inter > ra69)) {
      float aj = car[wv][c];
      float den = ((ra + aj) - inter) + 1e-9f;
      bool sup = ((double)inter >= M * (double)den);
      if (c < 32) mlo |= sup ? (1u << c) : 0u;
      else        mhi |= sup ? (1u << (c - 32)) : 0u;
    }
  }
  u64 m = ((u64)mhi << 32) | (u64)mlo;
  if (ti == tj) m &= (lane == 63) ? 0ull : (~0ull << (lane + 1));
  int nc = N - tj * 64;
  if (nc < 64) m &= (1ull << nc) - 1ull;
  if (i < N) mk[(size_t)bl * 16000 + (size_t)tj * 1000 + i] = m;
}

// ---- NMS phase B: 16-wave cooperative greedy scan, one block per (b,l) ----

__global__ void __launch_bounds__(1024) k_nms_scan(const u64* __restrict__ mk,
                                                   const u64* __restrict__ sow,
                                                   u64* __restrict__ keepw) {
  const int bl = blockIdx.x;
  const int b = bl / 5, l = bl % 5;
  const int N = c_LK[l];
  const int W = (N + 63) >> 6;
  const int lane = (int)threadIdx.x & 63;
  const int w = (int)threadIdx.x >> 6;
  const bool act = (w < W);
  __shared__ u64 sh_kept[16];

  const u64* rowp = mk + (size_t)bl * 16000 + (size_t)w * 1000;
  u64 acc = act ? ~sow[(size_t)b * 80 + l * 16 + w] : 0ull;

  u64 diag = 0ull;
  if (act) {
    int rd = w * 64 + lane;
    if (rd < N) diag = rowp[rd];
  }
  u64 nxt = (act && w > 0) ? rowp[lane] : 0ull;

  for (int g = 0; g < 16; ++g) {
    if (g >= W) break;
    u64 cur = nxt;
    if (act && w > g + 1) {
      int r = (g + 1) * 64 + lane;
      nxt = (r < N) ? rowp[r] : 0ull;
    } else {
      nxt = 0ull;
    }
    if (w == g) {
      u64 sup = acc;
      u64 pend = __ballot(diag != 0) & ~sup;
      while (pend) {
        int i = __builtin_ctzll(pend);
        u64 rr = __shfl(diag, i, 64);
        sup |= rr;
        pend &= ~sup;
        pend &= ~(1ull << i);
      }
      acc = sup;
      if (lane == 0) sh_kept[g] = ~sup;
    }
    __syncthreads();
    if (act && w > g) {
      u64 K = sh_kept[g];
      u64 c = ((K >> lane) & 1ull) ? cur : 0ull;
#pragma unroll
      for (int d = 1; d < 64; d <<= 1) c |= __shfl_xor(c, d, 64);
      acc |= c;
    }
    __syncthreads();
  }
  if (act && lane == 0) keepw[(size_t)b * 80 + l * 16 + w] = ~acc;
}

// ---- K5: merge 5 sorted kept lists by key; per-(level,batch) blocks ----

__global__ void __launch_bounds__(1024) k_out(const float* __restrict__ boxes,
                                              const float* __restrict__ scoref,
                                              const u64* __restrict__ skey,
                                              const u64* __restrict__ keepw,
                                              float* __restrict__ out) {
  const int l = blockIdx.x, b = blockIdx.y, t = threadIdx.x;
  __shared__ u64 sk[NSEL];
  __shared__ u64 kw[80];
  __shared__ u32 pp[5][17];
  __shared__ u32 sh_T;
  for (int i = t; i < NSEL; i += 1024) sk[i] = skey[(size_t)b * NSEL + i];
  if (t < 80) {
    int l2 = t >> 4, w = t & 15;
    int W = (c_LK[l2] + 63) >> 6;
    kw[t] = (w < W) ? keepw[(size_t)b * 80 + t] : 0ull;
  }
  __syncthreads();
  if (t < 5) {
    u32 acc = 0;
    pp[t][0] = 0;
    for (int w = 0; w < 16; ++w) {
      acc += (u32)__popcll(kw[t * 16 + w]);
      pp[t][w + 1] = acc;
    }
  }
  __syncthreads();
  if (t == 0) sh_T = pp[0][16] + pp[1][16] + pp[2][16] + pp[3][16] + pp[4][16];
  __syncthreads();
  const u32 T = sh_T;
  const int K = c_LK[l];

  for (int r = t; r < K; r += 1024) {
    int s = c_SOFF[l] + r;
    u64 word = kw[l * 16 + (r >> 6)];
    if ((word >> (r & 63)) & 1ull) {
      u32 rank = pp[l][r >> 6] +
                 (u32)__popcll(word & ((r & 63) ? ((1ull << (r & 63)) - 1ull) : 0ull));
      u64 key = sk[s];
#pragma unroll
      for (int l2 = 0; l2 < 5; ++l2) {
        if (l2 == l) continue;
        int lo = 0, hi = c_LK[l2];
        const int base2 = c_SOFF[l2];
        while (lo < hi) {
          int mid = (lo + hi) >> 1;
          if (sk[base2 + mid] < key) lo = mid + 1; else hi = mid;
        }
        u64 w2 = kw[l2 * 16 + (lo >> 6)];
        rank += pp[l2][lo >> 6] +
                (u32)__popcll(w2 & ((lo & 63) ? ((1ull << (lo & 63)) - 1ull) : 0ull));
      }
      if (rank < 1000u) {
        float4 bo = ((const float4*)boxes)[(size_t)b * NSEL + s];
        float* o = out + ((size_t)b * 1000 + rank) * 5;
        o[0] = bo.x; o[1] = bo.y; o[2] = bo.z; o[3] = bo.w;
        o[4] = scoref[(size_t)b * NSEL + s];
      }
    }
  }
  if (l == 0) {
    u32 start = (T < 1000u) ? T : 1000u;
    for (u32 i = start + t; i < 1000u; i += 1024u) {
      float* o = out + ((size_t)b * 1000 + i) * 5;
      o[0] = 0.0f; o[1] = 0.0f; o[2] = 0.0f; o[3] = 0.0f; o[4] = 0.0f;
    }
  }
}

// ---- host ----

extern "C" void kernel_launch(void* const* d_in, const int* in_sizes, int n_in,
                              void* d_out, int out_size, void* d_ws, size_t ws_size,
                              hipStream_t stream) {
  const float* reg = (const float*)d_in[0];
  const float* obj = (const float*)d_in[1];
  const float* priors = (const float*)d_in[2];
  float* out = (float*)d_out;

  char* ws = (char*)d_ws;
  size_t off = 0;
  auto alloc = [&](size_t bytes) {
    size_t r = off;
    off += (bytes + 255) & ~(size_t)255;
    return r;
  };
  u16* ghist = (u16*)(ws + alloc((size_t)NB * 86 * 4096 * 2));
  u32* ctrs = (u32*)(ws + alloc(160 * 4));
  int2* binfo = (int2*)(ws + alloc(80 * 8));
  u64* candg = (u64*)(ws + alloc((size_t)80 * 2048 * 8));
  u64* skey = (u64*)(ws + alloc((size_t)NB * NSEL * 8));
  float* boxes = (float*)(ws + alloc((size_t)NB * NSEL * 16));
  float* scoref = (float*)(ws + alloc((size_t)NB * NSEL * 4));
  float* nmsbox = (float*)(ws + alloc((size_t)NB * 5 * 1000 * 16));
  u64* sow = (u64*)(ws + alloc((size_t)NB * 80 * 8));
  u64* keepw = (u64*)(ws + alloc((size_t)NB * 80 * 8));
  u64* mk = (u64*)(ws + alloc((size_t)80 * 1000 * 16 * 8));

  k_hist<<<dim3(86, NB), 256, 0, stream>>>(obj, ghist);
  k_thresh<<<dim3(5, NB), 1024, 0, stream>>>(ghist, binfo, ctrs);
  k_emit<<<dim3(86, NB), 256, 0, stream>>>(obj, binfo, skey, candg, ctrs);
  k_selsort<<<dim3(5, NB), 1024, 0, stream>>>(candg, binfo, ctrs, skey, reg,
                                              priors, boxes, scoref, nmsbox, sow);
  k_nms_build<<<dim3(156, NB), 256, 0, stream>>>(nmsbox, mk);
  k_nms_scan<<<dim3(80), 1024, 0, stream>>>(mk, sow, keepw);
  k_out<<<dim3(5, NB), 1024, 0, stream>>>(boxes, scoref, skey, keepw, out);
}

// Round 17
// 101.057 us; speedup vs baseline: 1.1792x; 1.0575x over previous
//
#include <hip/hip_runtime.h>

typedef unsigned int u32;
typedef unsigned short u16;
typedef unsigned long long u64;

#define NB 16
#define NA 242991
#define NSEL 4741

__device__ __constant__ int c_LN[5]   = {182400, 45600, 11400, 2850, 741};
__device__ __constant__ int c_LOFF[5] = {0, 182400, 228000, 239400, 242250};
__device__ __constant__ int c_LK[5]   = {1000, 1000, 1000, 1000, 741};
__device__ __constant__ int c_SOFF[5] = {0, 1000, 2000, 3000, 4000};
__device__ __constant__ int c_CST[5]  = {0, 64, 80, 84, 85};   // chunk start per level
__device__ __constant__ int c_CCN[5]  = {64, 16, 4, 1, 1};     // chunk count per level

// ---- XLA-CPU-replicating transcendentals (bitwise-intent, no FMA contraction) ----

__device__ __forceinline__ float xla_tanhf(float x) {
#pragma clang fp contract(off)
  float t = fminf(fmaxf(x, -9.0f), 9.0f);
  float x2 = t * t;
  float p = -2.76076847742355e-16f;
  p = p * x2 + 2.00018790482477e-13f;
  p = p * x2 + -8.60467152213735e-11f;
  p = p * x2 + 5.12229709037114e-08f;
  p = p * x2 + 1.48572235717979e-05f;
  p = p * x2 + 6.37261928875436e-04f;
  p = p * x2 + 4.89352455891786e-03f;
  p = t * p;
  float q = 1.19825839466702e-06f;
  q = q * x2 + 1.18534705686654e-04f;
  q = q * x2 + 2.26843463243900e-03f;
  q = q * x2 + 4.89352518554385e-03f;
  float r = p / q;
  return (fabsf(x) < 0.0004f) ? x : r;
}

__device__ __forceinline__ float ref_sigmoid(float x) {
#pragma clang fp contract(off)
  float t = 0.5f * x;
  float th = xla_tanhf(t);
  return 0.5f + 0.5f * th;
}

__device__ __forceinline__ float xla_expf(float x) {
#pragma clang fp contract(off)
  float fx = x * 1.44269504088896341f + 0.5f;
  fx = floorf(fx);
  float tmp = fx * 0.693359375f;
  float z = fx * -2.12194440e-4f;
  float r = x - tmp;
  r = r - z;
  float r2 = r * r;
  float y = 1.9875691500e-4f;
  y = y * r + 1.3981999507e-3f;
  y = y * r + 8.3334519073e-3f;
  y = y * r + 4.1665795894e-2f;
  y = y * r + 1.6666665459e-1f;
  y = y * r + 5.0000001201e-1f;
  y = y * r2 + r;
  y = y + 1.0f;
  int k = (int)fx;
  float two_k = __uint_as_float((u32)((k + 127) << 23));
  return y * two_k;
}

// chunk -> (level, base, n) mapping; 86 chunks of 2850 (level boundaries divide)
__device__ __forceinline__ void chunk_map(int c, int& l, int& base, int& n) {
  if (c < 64)      { l = 0; base = c * 2850;                 n = 2850; }
  else if (c < 80) { l = 1; base = 182400 + (c - 64) * 2850; n = 2850; }
  else if (c < 84) { l = 2; base = 228000 + (c - 80) * 2850; n = 2850; }
  else if (c == 84){ l = 3; base = 239400;                   n = 2850; }
  else             { l = 4; base = 242250;                   n = 741;  }
}

// ---- S1: per-chunk u16 histogram slabs; block c==0 zeroes its batch's ctrs ----

__global__ void __launch_bounds__(256) k_hist(const float* __restrict__ obj,
                                              u16* __restrict__ ghist,
                                              u32* __restrict__ ctrs) {
  const int c = blockIdx.x, b = blockIdx.y;
  if (c == 0 && threadIdx.x < 5) {
    ctrs[b * 5 + threadIdx.x] = 0;
    ctrs[80 + b * 5 + threadIdx.x] = 0;
  }
  int l, base, n;
  chunk_map(c, l, base, n);
  __shared__ u32 h[4096];
  for (int i = threadIdx.x; i < 4096; i += 256) h[i] = 0;
  __syncthreads();
  const float* src = obj + (size_t)b * NA + base;
  for (int i = threadIdx.x; i < n; i += 256) {
    float s = ref_sigmoid(src[i]);
    atomicAdd(&h[__float_as_uint(s) >> 18], 1u);
  }
  __syncthreads();
  u32* gh = (u32*)(ghist + ((size_t)b * 86 + c) * 4096);
  for (int i = threadIdx.x; i < 2048; i += 256)
    gh[i] = (h[2 * i] & 0xFFFFu) | (h[2 * i + 1] << 16);
}

// ---- S3: emit selected keys. Each block recomputes bstar from the slabs via
//      an early-out top-down chunked scan (identical result in all blocks of
//      a given (b,l); equivalent to the old full suffix scan). ----

__global__ void __launch_bounds__(256) k_emit(const float* __restrict__ obj,
                                              const u16* __restrict__ ghist,
                                              u64* __restrict__ skey,
                                              u64* __restrict__ candg,
                                              u32* __restrict__ ctrs) {
  const int c = blockIdx.x, b = blockIdx.y;
  int l, base, n;
  chunk_map(c, l, base, n);
  const int bl = b * 5 + l;
  const int t = (int)threadIdx.x;

  // --- bstar recompute ---
  __shared__ u32 ch[256];
  __shared__ int sh_bstar;
  const u16* hb = ghist + (size_t)b * 86 * 4096;
  const int cs2 = c_CST[l], cn2 = c_CCN[l];
  const int K = c_LK[l];
  if (t == 0) sh_bstar = -1;
  __syncthreads();
  int bstar = 0;
  u32 acc = 0;
  for (int cb = 4096 - 256; cb >= 0; cb -= 256) {
    int bin = cb + t;
    u32 v = 0;
    for (int s2 = 0; s2 < cn2; ++s2) v += hb[(size_t)(cs2 + s2) * 4096 + bin];
    ch[255 - t] = v;   // reversed: index 0 = topmost bin of chunk
    __syncthreads();
    for (int d = 1; d < 256; d <<= 1) {
      u32 add = (t >= d) ? ch[t - d] : 0u;
      __syncthreads();
      ch[t] += add;
      __syncthreads();
    }
    u32 total = ch[255];
    u32 cum = ch[t];
    u32 prev = (t == 0) ? 0u : ch[t - 1];
    if (acc + cum >= (u32)K && acc + prev < (u32)K)
      sh_bstar = cb + (255 - t);
    __syncthreads();
    if (sh_bstar >= 0) { bstar = sh_bstar; break; }
    acc += total;
    __syncthreads();   // ch reused next chunk
  }
  // (loop always terminates with sh_bstar set since total counts >= K)
  bstar = sh_bstar;

  // --- selection emit (unchanged semantics) ---
  const float* src = obj + (size_t)b * NA + base;
  __shared__ u64 bufD[1024];
  __shared__ u64 bufC[2048];
  __shared__ u32 cntDC, gbD, gbC;
  if (t == 0) cntDC = 0;
  __syncthreads();

  const int lane = t & 63;
  const u64 lmask_lt = (lane == 0) ? 0ull : ((~0ull) >> (64 - lane));
  const int iters = (n + 255) >> 8;
  for (int it = 0; it < iters; ++it) {
    int i = it * 256 + t;
    bool valid = i < n;
    float s = ref_sigmoid(valid ? src[i] : 0.0f);
    u32 bits = __float_as_uint(s);
    int bin = (int)(bits >> 18);
    bool isD = valid && (bin > bstar);
    bool isC = valid && (bin == bstar);
    u64 mD = __ballot(isD);
    u64 mC = __ballot(isC);
    u32 bDC = 0;
    if (lane == 0) {
      u32 add = (u32)__popcll(mD) | ((u32)__popcll(mC) << 16);
      if (add) bDC = atomicAdd(&cntDC, add);
    }
    bDC = (u32)__shfl((int)bDC, 0, 64);
    u64 key = ((u64)(bits ^ 0xFFFFFFFFu) << 32) | (u32)(base + i);
    if (isD) {
      u32 p = (bDC & 0xFFFFu) + (u32)__popcll(mD & lmask_lt);
      if (p < 1024) bufD[p] = key;
    }
    if (isC) {
      u32 p = (bDC >> 16) + (u32)__popcll(mC & lmask_lt);
      if (p < 2048) bufC[p] = key;
    }
  }
  __syncthreads();
  const u32 nD = cntDC & 0xFFFFu, nC = cntDC >> 16;
  if (t == 0) {
    gbD = atomicAdd(&ctrs[bl], nD);
    gbC = atomicAdd(&ctrs[80 + bl], nC);
  }
  __syncthreads();
  const u32 gD = gbD, gC = gbC;
  u64* dstD = skey + (size_t)b * NSEL + c_SOFF[l] + gD;
  for (u32 i = threadIdx.x; i < nD; i += 256) dstD[i] = bufD[i];
  u64* dstC = candg + (size_t)bl * 2048;
  for (u32 i = threadIdx.x; i < nC; i += 256) {
    u32 p = gC + i;
    if (p < 2048 && i < 2048) dstC[p] = bufC[i];
  }
}

// ---- S4+K3 fused: adaptive-width (1024/2048/4096) hybrid bitonic sort ->
//      keys redistributed via LDS -> ALL 1024 threads decode (rank r = t).
//      G = ctrs[bl] (== emit's total direct count == old binfo.y). ----

__device__ __forceinline__ u64 shflx64(u64 v, int d) {
  u32 lo = (u32)v, hi = (u32)(v >> 32);
  lo = (u32)__shfl_xor((int)lo, d, 64);
  hi = (u32)__shfl_xor((int)hi, d, 64);
  return ((u64)hi << 32) | (u64)lo;
}

template <int CTRL>
__device__ __forceinline__ u64 dpp64(u64 v) {
  u32 lo = (u32)__builtin_amdgcn_mov_dpp((int)(u32)v, CTRL, 0xF, 0xF, true);
  u32 hi = (u32)__builtin_amdgcn_mov_dpp((int)(u32)(v >> 32), CTRL, 0xF, 0xF, true);
  return ((u64)hi << 32) | (u64)lo;
}

__global__ void __launch_bounds__(1024) k_selsort(
    const u64* __restrict__ candg,
    const u32* __restrict__ ctrs, u64* __restrict__ skey,
    const float* __restrict__ reg, const float* __restrict__ priors,
    float* __restrict__ boxes, float* __restrict__ scoref,
    float* __restrict__ nmsbox, u64* __restrict__ sow) {
  const int l = blockIdx.x, b = blockIdx.y, t = threadIdx.x;
  const int bl = b * 5 + l;
  const int K = c_LK[l];
  const int G = (int)ctrs[bl];
  u32 cc = ctrs[80 + bl];
  if (cc > 2048) cc = 2048;
  __shared__ u64 sm[4096];
  __shared__ u64 sh_sow[16];
  if (t < 16) sh_sow[t] = 0ull;
  const u64* seg = skey + (size_t)b * NSEL + c_SOFF[l];
  const u64* cnd = candg + (size_t)bl * 2048;

  const int total = G + (int)cc;
  const int NS = (total <= 1024) ? 1024 : (total <= 2048) ? 2048 : 4096;
  const int Q = NS >> 2;
  const bool act = (t < Q);
  const int i0 = 4 * t;

  u64 v0 = ~0ull, v1 = ~0ull, v2 = ~0ull, v3 = ~0ull;
  if (act) {
    auto ld = [&](int i) -> u64 {
      if (i < G) return seg[i];
      int ci = i - G;
      return (ci < (int)cc) ? cnd[ci] : ~0ull;
    };
    v0 = ld(i0); v1 = ld(i0 + 1); v2 = ld(i0 + 2); v3 = ld(i0 + 3);
  }

  auto cs = [](u64& a, u64& b2, bool up) {
    if ((a > b2) == up) { u64 x = a; a = b2; b2 = x; }
  };

  if (act) {
    cs(v0, v1, true);
    cs(v2, v3, false);
    bool up = ((i0 & 4) == 0);
    cs(v0, v2, up); cs(v1, v3, up);
    cs(v0, v1, up); cs(v2, v3, up);
  }
  for (int k = 8; k <= NS; k <<= 1) {
    const bool up = ((i0 & k) == 0);
    for (int j = k >> 1; j >= 256; j >>= 1) {
      if (act) { sm[t] = v0; sm[Q + t] = v1; sm[2 * Q + t] = v2; sm[3 * Q + t] = v3; }
      __syncthreads();
      if (act) {
        const int u = t ^ (j >> 2);
        u64 o0 = sm[u], o1 = sm[Q + u], o2 = sm[2 * Q + u], o3 = sm[3 * Q + u];
        const bool keepmin = (((i0 & j) == 0) == up);
        v0 = keepmin ? (v0 < o0 ? v0 : o0) : (v0 > o0 ? v0 : o0);
        v1 = keepmin ? (v1 < o1 ? v1 : o1) : (v1 > o1 ? v1 : o1);
        v2 = keepmin ? (v2 < o2 ? v2 : o2) : (v2 > o2 ? v2 : o2);
        v3 = keepmin ? (v3 < o3 ? v3 : o3) : (v3 > o3 ? v3 : o3);
      }
      __syncthreads();
    }
    if (act) {
      int jstart = (k >> 1) < 128 ? (k >> 1) : 128;
      for (int j = jstart; j >= 4; j >>= 1) {
        const int d = j >> 2;
        u64 o0, o1, o2, o3;
        if (d == 1) {
          o0 = dpp64<0xB1>(v0); o1 = dpp64<0xB1>(v1);
          o2 = dpp64<0xB1>(v2); o3 = dpp64<0xB1>(v3);
        } else if (d == 2) {
          o0 = dpp64<0x4E>(v0); o1 = dpp64<0x4E>(v1);
          o2 = dpp64<0x4E>(v2); o3 = dpp64<0x4E>(v3);
        } else {
          o0 = shflx64(v0, d); o1 = shflx64(v1, d);
          o2 = shflx64(v2, d); o3 = shflx64(v3, d);
        }
        const bool keepmin = (((t & d) == 0) == up);
        v0 = keepmin ? (v0 < o0 ? v0 : o0) : (v0 > o0 ? v0 : o0);
        v1 = keepmin ? (v1 < o1 ? v1 : o1) : (v1 > o1 ? v1 : o1);
        v2 = keepmin ? (v2 < o2 ? v2 : o2) : (v2 > o2 ? v2 : o2);
        v3 = keepmin ? (v3 < o3 ? v3 : o3) : (v3 > o3 ? v3 : o3);
      }
      cs(v0, v2, up); cs(v1, v3, up);
      cs(v0, v1, up); cs(v2, v3, up);
    }
  }

  // redistribute sorted keys through LDS so ALL 16 waves share the decode
  __syncthreads();
  if (act) { sm[i0] = v0; sm[i0 + 1] = v1; sm[i0 + 2] = v2; sm[i0 + 3] = v3; }
  __syncthreads();

  u64* dst = skey + (size_t)b * NSEL + c_SOFF[l];

  // decode (identical arithmetic), rank r = t, one entry per thread
  if (t < K) {
#pragma clang fp contract(off)
    const float lf = (float)l * 10000.0f;
    const int r = t;
    u64 kk = sm[r];
    dst[r] = kk;
    u32 idx = (u32)kk;
    if (idx >= (u32)NA) idx = NA - 1;
    u32 bits = (u32)(kk >> 32) ^ 0xFFFFFFFFu;
    float s = __uint_as_float(bits);
    float4 r4 = ((const float4*)reg)[(size_t)b * NA + idx];
    float4 q4 = ((const float4*)priors)[idx];
    float pw = q4.z - q4.x;
    float ph = q4.w - q4.y;
    float pcx = q4.x + 0.5f * pw;
    float pcy = q4.y + 0.5f * ph;
    float dw = fminf(r4.z, 4.135166556742356f);
    float dh = fminf(r4.w, 4.135166556742356f);
    float cx = r4.x * pw + pcx;
    float cy = r4.y * ph + pcy;
    float w = pw * xla_expf(dw);
    float h = ph * xla_expf(dh);
    float x1 = cx - 0.5f * w;
    float y1 = cy - 0.5f * h;
    float x2 = cx + 0.5f * w;
    float y2 = cy + 0.5f * h;
    x1 = fminf(fmaxf(x1, 0.0f), 1216.0f);
    y1 = fminf(fmaxf(y1, 0.0f), 800.0f);
    x2 = fminf(fmaxf(x2, 0.0f), 1216.0f);
    y2 = fminf(fmaxf(y2, 0.0f), 800.0f);
    bool ok = ((x2 - x1) > 0.01f) && ((y2 - y1) > 0.01f);
    int sidx = c_SOFF[l] + r;
    ((float4*)boxes)[(size_t)b * NSEL + sidx] = make_float4(x1, y1, x2, y2);
    scoref[(size_t)b * NSEL + sidx] = s;
    ((float4*)nmsbox)[(size_t)(b * 5 + l) * 1000 + r] =
        make_float4(x1 + lf, y1 + lf, x2 + lf, y2 + lf);
    if (ok) atomicOr(&sh_sow[r >> 6], 1ull << (r & 63));
  }
  __syncthreads();
  if (t < 16) sow[(size_t)b * 80 + l * 16 + t] = sh_sow[t];
}

// ---- NMS phase A: upper-triangle 64x64 tiles, one wave per tile ----
// Gate: sup requires inter >= ~0.6999997*ra (inter<=min(ra,aj) exactly by
// RN-monotonicity => den>=ra(1-3eps)); inter<=RN(0.69f*ra)<=0.6900002*ra
// implies sup=false -> gate-skipped lanes are exactly the sup=false ones.

__device__ __forceinline__ void tile_map(int k, int& l, int& ti, int& tj) {
  int W;
  if (k < 544) { l = k / 136; k -= l * 136; W = 16; }
  else         { l = 4; k -= 544; W = 12; }
  int a = 0;
  while (k >= W - a) { k -= W - a; a++; }
  ti = a; tj = a + k;
}

__global__ void __launch_bounds__(256) k_nms_build(const float* __restrict__ nmsbox,
                                                   u64* __restrict__ mk) {
#pragma clang fp contract(off)
  const int b = blockIdx.y;
  const int wv = (int)threadIdx.x >> 6;
  const int tid = blockIdx.x * 4 + wv;
  __shared__ float4 cbox[4][64];
  __shared__ float car[4][64];
  if (tid >= 622) return;
  const int lane = (int)threadIdx.x & 63;
  int l, ti, tj;
  tile_map(tid, l, ti, tj);
  const int N = c_LK[l];
  const int bl = b * 5 + l;
  const float4* src = (const float4*)(nmsbox + (size_t)bl * 4000);
  const int i = ti * 64 + lane;
  const int j = tj * 64 + lane;
  const int il = (i < N) ? i : (N - 1);
  const int jl = (j < N) ? j : (N - 1);
  float4 rb = src[il];
  float4 cb0 = src[jl];
  float ra = fmaxf(rb.z - rb.x, 0.0f) * fmaxf(rb.w - rb.y, 0.0f);
  float ca0 = fmaxf(cb0.z - cb0.x, 0.0f) * fmaxf(cb0.w - cb0.y, 0.0f);
  float ra69 = 0.69f * ra;
  cbox[wv][lane] = cb0;
  car[wv][lane] = ca0;
  u32 mlo = 0u, mhi = 0u;
  const double M = 0.7000000178813934326171875;
#pragma unroll
  for (int c = 0; c < 64; ++c) {
    float4 cb = cbox[wv][c];
    float xx1 = fmaxf(rb.x, cb.x);
    float yy1 = fmaxf(rb.y, cb.y);
    float xx2 = fminf(rb.z, cb.z);
    float yy2 = fminf(rb.w, cb.w);
    float inter = fmaxf(xx2 - xx1, 0.0f) * fmaxf(yy2 - yy1, 0.0f);
    if (__any(inter > ra69)) {
      float aj = car[wv][c];
      float den = ((ra + aj) - inter) + 1e-9f;
      bool sup = ((double)inter >= M * (double)den);
      if (c < 32) mlo |= sup ? (1u << c) : 0u;
      else        mhi |= sup ? (1u << (c - 32)) : 0u;
    }
  }
  u64 m = ((u64)mhi << 32) | (u64)mlo;
  if (ti == tj) m &= (lane == 63) ? 0ull : (~0ull << (lane + 1));
  int nc = N - tj * 64;
  if (nc < 64) m &= (1ull << nc) - 1ull;
  if (i < N) mk[(size_t)bl * 16000 + (size_t)tj * 1000 + i] = m;
}

// ---- NMS phase B: 16-wave cooperative greedy scan, one block per (b,l) ----

__global__ void __launch_bounds__(1024) k_nms_scan(const u64* __restrict__ mk,
                                                   const u64* __restrict__ sow,
                                                   u64* __restrict__ keepw) {
  const int bl = blockIdx.x;
  const int b = bl / 5, l = bl % 5;
  const int N = c_LK[l];
  const int W = (N + 63) >> 6;
  const int lane = (int)threadIdx.x & 63;
  const int w = (int)threadIdx.x >> 6;
  const bool act = (w < W);
  __shared__ u64 sh_kept[16];

  const u64* rowp = mk + (size_t)bl * 16000 + (size_t)w * 1000;
  u64 acc = act ? ~sow[(size_t)b * 80 + l * 16 + w] : 0ull;

  u64 diag = 0ull;
  if (act) {
    int rd = w * 64 + lane;
    if (rd < N) diag = rowp[rd];
  }
  u64 nxt = (act && w > 0) ? rowp[lane] : 0ull;

  for (int g = 0; g < 16; ++g) {
    if (g >= W) break;
    u64 cur = nxt;
    if (act && w > g + 1) {
      int r = (g + 1) * 64 + lane;
      nxt = (r < N) ? rowp[r] : 0ull;
    } else {
      nxt = 0ull;
    }
    if (w == g) {
      u64 sup = acc;
      u64 pend = __ballot(diag != 0) & ~sup;
      while (pend) {
        int i = __builtin_ctzll(pend);
        u64 rr = __shfl(diag, i, 64);
        sup |= rr;
        pend &= ~sup;
        pend &= ~(1ull << i);
      }
      acc = sup;
      if (lane == 0) sh_kept[g] = ~sup;
    }
    __syncthreads();
    if (act && w > g) {
      u64 K = sh_kept[g];
      u64 c = ((K >> lane) & 1ull) ? cur : 0ull;
#pragma unroll
      for (int d = 1; d < 64; d <<= 1) c |= __shfl_xor(c, d, 64);
      acc |= c;
    }
    __syncthreads();
  }
  if (act && lane == 0) keepw[(size_t)b * 80 + l * 16 + w] = ~acc;
}

// ---- K5: merge 5 sorted kept lists by key; per-(level,batch) blocks ----

__global__ void __launch_bounds__(1024) k_out(const float* __restrict__ boxes,
                                              const float* __restrict__ scoref,
                                              const u64* __restrict__ skey,
                                              const u64* __restrict__ keepw,
                                              float* __restrict__ out) {
  const int l = blockIdx.x, b = blockIdx.y, t = threadIdx.x;
  __shared__ u64 sk[NSEL];
  __shared__ u64 kw[80];
  __shared__ u32 pp[5][17];
  __shared__ u32 sh_T;
  for (int i = t; i < NSEL; i += 1024) sk[i] = skey[(size_t)b * NSEL + i];
  if (t < 80) {
    int l2 = t >> 4, w = t & 15;
    int W = (c_LK[l2] + 63) >> 6;
    kw[t] = (w < W) ? keepw[(size_t)b * 80 + t] : 0ull;
  }
  __syncthreads();
  if (t < 5) {
    u32 acc = 0;
    pp[t][0] = 0;
    for (int w = 0; w < 16; ++w) {
      acc += (u32)__popcll(kw[t * 16 + w]);
      pp[t][w + 1] = acc;
    }
  }
  __syncthreads();
  if (t == 0) sh_T = pp[0][16] + pp[1][16] + pp[2][16] + pp[3][16] + pp[4][16];
  __syncthreads();
  const u32 T = sh_T;
  const int K = c_LK[l];

  for (int r = t; r < K; r += 1024) {
    int s = c_SOFF[l] + r;
    u64 word = kw[l * 16 + (r >> 6)];
    if ((word >> (r & 63)) & 1ull) {
      u32 rank = pp[l][r >> 6] +
                 (u32)__popcll(word & ((r & 63) ? ((1ull << (r & 63)) - 1ull) : 0ull));
      u64 key = sk[s];
#pragma unroll
      for (int l2 = 0; l2 < 5; ++l2) {
        if (l2 == l) continue;
        int lo = 0, hi = c_LK[l2];
        const int base2 = c_SOFF[l2];
        while (lo < hi) {
          int mid = (lo + hi) >> 1;
          if (sk[base2 + mid] < key) lo = mid + 1; else hi = mid;
        }
        u64 w2 = kw[l2 * 16 + (lo >> 6)];
        rank += pp[l2][lo >> 6] +
                (u32)__popcll(w2 & ((lo & 63) ? ((1ull << (lo & 63)) - 1ull) : 0ull));
      }
      if (rank < 1000u) {
        float4 bo = ((const float4*)boxes)[(size_t)b * NSEL + s];
        float* o = out + ((size_t)b * 1000 + rank) * 5;
        o[0] = bo.x; o[1] = bo.y; o[2] = bo.z; o[3] = bo.w;
        o[4] = scoref[(size_t)b * NSEL + s];
      }
    }
  }
  if (l == 0) {
    u32 start = (T < 1000u) ? T : 1000u;
    for (u32 i = start + t; i < 1000u; i += 1024u) {
      float* o = out + ((size_t)b * 1000 + i) * 5;
      o[0] = 0.0f; o[1] = 0.0f; o[2] = 0.0f; o[3] = 0.0f; o[4] = 0.0f;
    }
  }
}

// ---- host ----

extern "C" void kernel_launch(void* const* d_in, const int* in_sizes, int n_in,
                              void* d_out, int out_size, void* d_ws, size_t ws_size,
                              hipStream_t stream) {
  const float* reg = (const float*)d_in[0];
  const float* obj = (const float*)d_in[1];
  const float* priors = (const float*)d_in[2];
  float* out = (float*)d_out;

  char* ws = (char*)d_ws;
  size_t off = 0;
  auto alloc = [&](size_t bytes) {
    size_t r = off;
    off += (bytes + 255) & ~(size_t)255;
    return r;
  };
  u16* ghist = (u16*)(ws + alloc((size_t)NB * 86 * 4096 * 2));
  u32* ctrs = (u32*)(ws + alloc(160 * 4));
  u64* candg = (u64*)(ws + alloc((size_t)80 * 2048 * 8));
  u64* skey = (u64*)(ws + alloc((size_t)NB * NSEL * 8));
  float* boxes = (float*)(ws + alloc((size_t)NB * NSEL * 16));
  float* scoref = (float*)(ws + alloc((size_t)NB * NSEL * 4));
  float* nmsbox = (float*)(ws + alloc((size_t)NB * 5 * 1000 * 16));
  u64* sow = (u64*)(ws + alloc((size_t)NB * 80 * 8));
  u64* keepw = (u64*)(ws + alloc((size_t)NB * 80 * 8));
  u64* mk = (u64*)(ws + alloc((size_t)80 * 1000 * 16 * 8));

  k_hist<<<dim3(86, NB), 256, 0, stream>>>(obj, ghist, ctrs);
  k_emit<<<dim3(86, NB), 256, 0, stream>>>(obj, ghist, skey, candg, ctrs);
  k_selsort<<<dim3(5, NB), 1024, 0, stream>>>(candg, ctrs, skey, reg,
                                              priors, boxes, scoref, nmsbox, sow);
  k_nms_build<<<dim3(156, NB), 256, 0, stream>>>(nmsbox, mk);
  k_nms_scan<<<dim3(80), 1024, 0, stream>>>(mk, sow, keepw);
  k_out<<<dim3(5, NB), 1024, 0, stream>>>(boxes, scoref, skey, keepw, out);
}